// Round 3
// baseline (674.072 us; speedup 1.0000x reference)
//
#include <hip/hip_runtime.h>
#include <stdint.h>

// Problem constants
#define B_  32
#define N_  4096
#define DIN 256
#define S_  16
#define D_  256
#define H_  512
#define MTOK (B_ * N_)   // 131072 token rows
#define MS   (B_ * S_)   // 512 slot rows

typedef __attribute__((ext_vector_type(8))) short bf16x8;
typedef __attribute__((ext_vector_type(4))) float f32x4;

__device__ __forceinline__ f32x4 mfma16(bf16x8 a, bf16x8 b, f32x4 c) {
    return __builtin_amdgcn_mfma_f32_16x16x32_bf16(a, b, c, 0, 0, 0);
}

__device__ __forceinline__ float bf2f(unsigned short u) {
    union { unsigned int i; float f; } c; c.i = ((unsigned int)u) << 16; return c.f;
}
__device__ __forceinline__ unsigned short f2bf(float f) {
    union { float f; unsigned int i; } c; c.f = f;
    unsigned int r = (c.i + 0x7fffu + ((c.i >> 16) & 1u)) >> 16;
    return (unsigned short)r;
}
__device__ __forceinline__ unsigned int pk2(float a, float b) {
    return (unsigned int)f2bf(a) | ((unsigned int)f2bf(b) << 16);
}
__device__ __forceinline__ float sigm(float x) { return 1.0f / (1.0f + __expf(-x)); }
__device__ __forceinline__ float tanh_(float x) {
    float e = __expf(-2.0f * fabsf(x));
    float t = (1.0f - e) / (1.0f + e);
    return copysignf(t, x);
}

// ---------------------------------------------------------------------------
// K0: slots init + fp32->bf16 weight conversion
// ---------------------------------------------------------------------------
__global__ __launch_bounds__(256) void k_prep(
    const float* __restrict__ noise, const float* __restrict__ mu, const float* __restrict__ sigma,
    const float* __restrict__ Wk, const float* __restrict__ Wv, const float* __restrict__ Wq,
    const float* __restrict__ Wih, const float* __restrict__ Whh,
    const float* __restrict__ W1, const float* __restrict__ W2,
    float* __restrict__ slots,
    unsigned short* __restrict__ wkb, unsigned short* __restrict__ wvb,
    unsigned short* __restrict__ wqb, unsigned short* __restrict__ wihb,
    unsigned short* __restrict__ whhb, unsigned short* __restrict__ w1b,
    unsigned short* __restrict__ w2b)
{
    int i = blockIdx.x * 256 + threadIdx.x;
    if (i < 131072) slots[i] = mu[i & 255] + sigma[i & 255] * noise[i];
    int j = i - 131072;
    if (j >= 0 && j < 65536) wkb[j] = f2bf(Wk[j]);
    j -= 65536;
    if (j >= 0 && j < 65536) wvb[j] = f2bf(Wv[j]);
    j -= 65536;
    if (j >= 0 && j < 65536) wqb[j] = f2bf(Wq[j]);
    j -= 65536;
    if (j >= 0 && j < 196608) wihb[j] = f2bf(Wih[j]);
    j -= 196608;
    if (j >= 0 && j < 196608) whhb[j] = f2bf(Whh[j]);
    j -= 196608;
    if (j >= 0 && j < 131072) w1b[j] = f2bf(W1[j]);
    j -= 131072;
    if (j >= 0 && j < 131072) w2b[j] = f2bf(W2[j]);
}

// ---------------------------------------------------------------------------
// K1: fused LayerNorm(inputs) + k = x@Wk^T + bk (row-major bf16)
//                               + v = x@Wv^T + bv (TRANSPOSED: vT[b][d][tok], bf16)
// block = 256 threads / 4 waves; tile = 64 token rows x 512 outputs (k|v)
// ---------------------------------------------------------------------------
__global__ __launch_bounds__(256) void k_lnkv(
    const float* __restrict__ inp, const float* __restrict__ gln, const float* __restrict__ bln,
    const unsigned short* __restrict__ Wk, const unsigned short* __restrict__ Wv,
    const float* __restrict__ bk, const float* __restrict__ bv,
    unsigned short* __restrict__ kout, unsigned short* __restrict__ vT)
{
    __shared__ unsigned short xa[64 * 264];   // padded row stride 264 elems (528B)
    __shared__ float gl[256], bl[256];
    __shared__ unsigned short cst[64 * 256];  // C-tile staging (32KB)

    int t = threadIdx.x;
    long m0 = (long)blockIdx.x * 64;
    gl[t] = gln[t]; bl[t] = bln[t];

    // ---- LN stage: thread t handles row t>>2, quarter t&3 (64 floats) ----
    int row = t >> 2, seg = t & 3;
    const float4* src = (const float4*)(inp + (m0 + row) * 256 + seg * 64);
    float4 vv[16];
    float s = 0.f, ss = 0.f;
#pragma unroll
    for (int i = 0; i < 16; i++) {
        vv[i] = src[i];
        s  += vv[i].x + vv[i].y + vv[i].z + vv[i].w;
        ss += vv[i].x * vv[i].x + vv[i].y * vv[i].y + vv[i].z * vv[i].z + vv[i].w * vv[i].w;
    }
    s  += __shfl_xor(s, 1);  s  += __shfl_xor(s, 2);
    ss += __shfl_xor(ss, 1); ss += __shfl_xor(ss, 2);
    float mean = s * (1.f / 256.f);
    float var  = ss * (1.f / 256.f) - mean * mean;
    float rstd = rsqrtf(var + 1e-5f);
    __syncthreads();  // gl/bl ready
#pragma unroll
    for (int i = 0; i < 16; i++) {
        int c = seg * 64 + i * 4;
        float a0 = (vv[i].x - mean) * rstd * gl[c + 0] + bl[c + 0];
        float a1 = (vv[i].y - mean) * rstd * gl[c + 1] + bl[c + 1];
        float a2 = (vv[i].z - mean) * rstd * gl[c + 2] + bl[c + 2];
        float a3 = (vv[i].w - mean) * rstd * gl[c + 3] + bl[c + 3];
        uint2 pk; pk.x = pk2(a0, a1); pk.y = pk2(a2, a3);
        *(uint2*)&xa[row * 264 + c] = pk;
    }
    __syncthreads();

    // ---- GEMM: wave w covers output cols [128w, 128w+128) ----
    int wv_ = t >> 6, l = t & 63, l15 = l & 15, l4 = l >> 4;
    const unsigned short* Wsel = (wv_ < 2) ? Wk : Wv;
    int ncol0 = (wv_ & 1) * 128;
    f32x4 acc[4][8];
#pragma unroll
    for (int mf = 0; mf < 4; mf++)
#pragma unroll
        for (int nf = 0; nf < 8; nf++) acc[mf][nf] = (f32x4){0.f, 0.f, 0.f, 0.f};

    for (int kk = 0; kk < 8; kk++) {
        bf16x8 a[4];
#pragma unroll
        for (int mf = 0; mf < 4; mf++)
            a[mf] = *(const bf16x8*)&xa[(mf * 16 + l15) * 264 + kk * 32 + l4 * 8];
#pragma unroll
        for (int nf = 0; nf < 8; nf++) {
            bf16x8 b = *(const bf16x8*)&Wsel[(ncol0 + nf * 16 + l15) * 256 + kk * 32 + l4 * 8];
#pragma unroll
            for (int mf = 0; mf < 4; mf++) acc[mf][nf] = mfma16(a[mf], b, acc[mf][nf]);
        }
    }
    __syncthreads();  // xa dead; reuse epilogue staging

    // ---- k epilogue (waves 0,1) ----
    if (wv_ < 2) {
#pragma unroll
        for (int nf = 0; nf < 8; nf++) {
            int col = ncol0 + nf * 16 + l15;
            float bias = bk[col];
#pragma unroll
            for (int mf = 0; mf < 4; mf++)
#pragma unroll
                for (int r = 0; r < 4; r++)
                    cst[(mf * 16 + l4 * 4 + r) * 256 + col] = f2bf(acc[mf][nf][r] + bias);
        }
    }
    __syncthreads();
    {   // flat coalesced write: k rows are contiguous
        const uint4* s4 = (const uint4*)cst;
        uint4* d4 = (uint4*)(kout + m0 * 256);
        for (int c = t; c < 2048; c += 256) d4[c] = s4[c];
    }
    __syncthreads();
    // ---- v epilogue (waves 2,3) ----
    if (wv_ >= 2) {
#pragma unroll
        for (int nf = 0; nf < 8; nf++) {
            int col = ncol0 + nf * 16 + l15;
            float bias = bv[col];
#pragma unroll
            for (int mf = 0; mf < 4; mf++)
#pragma unroll
                for (int r = 0; r < 4; r++)
                    cst[(mf * 16 + l4 * 4 + r) * 256 + col] = f2bf(acc[mf][nf][r] + bias);
        }
    }
    __syncthreads();
    {   // transposed write: vT[b][d][tok], 128B contiguous per d-row
        int bb = (int)(m0 >> 12);
        int tok0 = (int)(m0 & 4095);
        int d = t;
        unsigned short tmp[64];
#pragma unroll
        for (int tk = 0; tk < 64; tk++) tmp[tk] = cst[tk * 256 + d];
        uint4* dst = (uint4*)(vT + ((long)bb * 256 + d) * 4096 + tok0);
#pragma unroll
        for (int c = 0; c < 8; c++) dst[c] = ((const uint4*)tmp)[c];
    }
}

// ---------------------------------------------------------------------------
// K2: q = LN(slots)@Wq^T + bq  -> q_bf16 [512][256]
// ---------------------------------------------------------------------------
__global__ __launch_bounds__(256) void k_q(
    const float* __restrict__ slots, const float* __restrict__ gln, const float* __restrict__ bln,
    const unsigned short* __restrict__ Wq, const float* __restrict__ bq,
    unsigned short* __restrict__ qout)
{
    __shared__ unsigned short ms[32 * 264];
    int t = threadIdx.x;
    int m0 = blockIdx.x * 32;
    int row = t >> 3, sg = t & 7;
    const float4* src = (const float4*)(slots + (m0 + row) * 256 + sg * 32);
    float4 vv[8];
    float s = 0.f, ss = 0.f;
#pragma unroll
    for (int i = 0; i < 8; i++) {
        vv[i] = src[i];
        s  += vv[i].x + vv[i].y + vv[i].z + vv[i].w;
        ss += vv[i].x * vv[i].x + vv[i].y * vv[i].y + vv[i].z * vv[i].z + vv[i].w * vv[i].w;
    }
    s  += __shfl_xor(s, 1);  s  += __shfl_xor(s, 2);  s  += __shfl_xor(s, 4);
    ss += __shfl_xor(ss, 1); ss += __shfl_xor(ss, 2); ss += __shfl_xor(ss, 4);
    float mean = s * (1.f / 256.f);
    float rstd = rsqrtf(ss * (1.f / 256.f) - mean * mean + 1e-5f);
#pragma unroll
    for (int i = 0; i < 8; i++) {
        int c = sg * 32 + i * 4;
        float a0 = (vv[i].x - mean) * rstd * gln[c + 0] + bln[c + 0];
        float a1 = (vv[i].y - mean) * rstd * gln[c + 1] + bln[c + 1];
        float a2 = (vv[i].z - mean) * rstd * gln[c + 2] + bln[c + 2];
        float a3 = (vv[i].w - mean) * rstd * gln[c + 3] + bln[c + 3];
        uint2 pk; pk.x = pk2(a0, a1); pk.y = pk2(a2, a3);
        *(uint2*)&ms[row * 264 + c] = pk;
    }
    __syncthreads();

    int wv_ = t >> 6, l = t & 63, l15 = l & 15, l4 = l >> 4;
    f32x4 o[2][4];
#pragma unroll
    for (int mf = 0; mf < 2; mf++)
#pragma unroll
        for (int nf = 0; nf < 4; nf++) o[mf][nf] = (f32x4){0.f, 0.f, 0.f, 0.f};
    for (int kk = 0; kk < 8; kk++) {
        bf16x8 a0 = *(const bf16x8*)&ms[l15 * 264 + kk * 32 + l4 * 8];
        bf16x8 a1 = *(const bf16x8*)&ms[(16 + l15) * 264 + kk * 32 + l4 * 8];
#pragma unroll
        for (int nf = 0; nf < 4; nf++) {
            bf16x8 b = *(const bf16x8*)&Wq[(wv_ * 64 + nf * 16 + l15) * 256 + kk * 32 + l4 * 8];
            o[0][nf] = mfma16(a0, b, o[0][nf]);
            o[1][nf] = mfma16(a1, b, o[1][nf]);
        }
    }
#pragma unroll
    for (int nf = 0; nf < 4; nf++) {
        int col = wv_ * 64 + nf * 16 + l15;
        float bb = bq[col];
#pragma unroll
        for (int mf = 0; mf < 2; mf++)
#pragma unroll
            for (int r = 0; r < 4; r++)
                qout[(m0 + mf * 16 + l4 * 4 + r) * 256 + col] = f2bf(o[mf][nf][r] + bb);
    }
}

// ---------------------------------------------------------------------------
// K3: fused attention pass for one (b, 256-token chunk):
//     logits = scale * q@k^T -> softmax over S (in-fragment shuffle) -> attn
//     -> write attn fp32 to d_out; partial updates = attn @ v via vT
// ---------------------------------------------------------------------------
__global__ __launch_bounds__(256) void k_attn(
    const unsigned short* __restrict__ kbf, const unsigned short* __restrict__ vT,
    const unsigned short* __restrict__ qbf, float* __restrict__ attn_out,
    float* __restrict__ part)
{
    __shared__ unsigned short qs[16 * 264];
    __shared__ unsigned short as_[16 * 264];
    int t = threadIdx.x, l = t & 63, wv_ = t >> 6, l15 = l & 15, l4 = l >> 4;
    int b = blockIdx.x >> 4;
    int chunk = blockIdx.x & 15;
    int tok_base = chunk * 256;

    for (int c = t; c < 512; c += 256) {
        int r = c >> 5, cc = c & 31;
        *(uint4*)&qs[r * 264 + cc * 8] = *(const uint4*)&qbf[(b * 16 + r) * 256 + cc * 8];
    }
    __syncthreads();

    // ---- phase A: logits + softmax over slots ----
    int wtok = tok_base + wv_ * 64;
#pragma unroll
    for (int tf = 0; tf < 4; tf++) {
        int tok0 = wtok + tf * 16;
        f32x4 c4 = (f32x4){0.f, 0.f, 0.f, 0.f};
        const unsigned short* krow = kbf + ((long)b * 4096 + tok0 + l15) * 256 + l4 * 8;
#pragma unroll
        for (int kk = 0; kk < 8; kk++) {
            bf16x8 a = *(const bf16x8*)&qs[l15 * 264 + kk * 32 + l4 * 8];
            bf16x8 bb = *(const bf16x8*)&krow[kk * 32];
            c4 = mfma16(a, bb, c4);
        }
#pragma unroll
        for (int r = 0; r < 4; r++) c4[r] *= 0.0625f;   // D^-0.5
        float mx = fmaxf(fmaxf(c4[0], c4[1]), fmaxf(c4[2], c4[3]));
        mx = fmaxf(mx, __shfl_xor(mx, 16));
        mx = fmaxf(mx, __shfl_xor(mx, 32));
        float e[4]; float sm = 0.f;
#pragma unroll
        for (int r = 0; r < 4; r++) { e[r] = __expf(c4[r] - mx); sm += e[r]; }
        sm += __shfl_xor(sm, 16);
        sm += __shfl_xor(sm, 32);
        float inv = 1.0f / sm;
#pragma unroll
        for (int r = 0; r < 4; r++) {
            float av = e[r] * inv;
            int srow = l4 * 4 + r;
            attn_out[((long)b * 16 + srow) * 4096 + tok0 + l15] = av;
            as_[srow * 264 + wv_ * 64 + tf * 16 + l15] = f2bf(av);
        }
    }
    __syncthreads();

    // ---- phase B: partial updates = attn[16 x 256] @ v[256 x 256] ----
    int d0 = wv_ * 64;
    f32x4 u[4];
#pragma unroll
    for (int df = 0; df < 4; df++) u[df] = (f32x4){0.f, 0.f, 0.f, 0.f};
    for (int kk = 0; kk < 8; kk++) {
        bf16x8 a = *(const bf16x8*)&as_[l15 * 264 + kk * 32 + l4 * 8];
#pragma unroll
        for (int df = 0; df < 4; df++) {
            bf16x8 bb = *(const bf16x8*)&vT[((long)b * 256 + d0 + df * 16 + l15) * 4096
                                            + tok_base + kk * 32 + l4 * 8];
            u[df] = mfma16(a, bb, u[df]);
        }
    }
#pragma unroll
    for (int df = 0; df < 4; df++)
#pragma unroll
        for (int r = 0; r < 4; r++) {
            int srow = l4 * 4 + r;
            part[(((long)b * 16 + chunk) * 16 + srow) * 256 + d0 + df * 16 + l15] = u[df][r];
        }
}

// ---------------------------------------------------------------------------
// K4: reduce 16 partial chunks -> updates [512][256]
// ---------------------------------------------------------------------------
__global__ __launch_bounds__(256) void k_reduce(const float* __restrict__ part,
                                                float* __restrict__ upd)
{
    int idx = blockIdx.x * 256 + threadIdx.x;
    int b = idx >> 12, sd = idx & 4095;
    float s = 0.f;
#pragma unroll
    for (int c = 0; c < 16; c++) s += part[((long)b * 16 + c) * 4096 + sd];
    upd[idx] = s;
}

// ---------------------------------------------------------------------------
// K5: GRU cell: h = GRUCell(updates, slots)
// tile [64 m][64 j], 3 gate column-groups x {W_ih, W_hh}
// ---------------------------------------------------------------------------
__global__ __launch_bounds__(256) void k_gru(
    const float* __restrict__ upd, const float* __restrict__ slots,
    const unsigned short* __restrict__ Wih, const unsigned short* __restrict__ Whh,
    const float* __restrict__ bih, const float* __restrict__ bhh,
    float* __restrict__ hout)
{
    __shared__ unsigned short au[64 * 264], as_[64 * 264];
    int t = threadIdx.x, l = t & 63, wv_ = t >> 6, l15 = l & 15, l4 = l >> 4;
    int m0 = (blockIdx.x >> 2) * 64;
    int j0 = (blockIdx.x & 3) * 64;

    for (int c = t; c < 4096; c += 256) {
        int r = c >> 6, cc = (c & 63) * 4;
        float4 v1 = *(const float4*)&upd[(m0 + r) * 256 + cc];
        float4 v2 = *(const float4*)&slots[(m0 + r) * 256 + cc];
        uint2 p1; p1.x = pk2(v1.x, v1.y); p1.y = pk2(v1.z, v1.w);
        uint2 p2; p2.x = pk2(v2.x, v2.y); p2.y = pk2(v2.z, v2.w);
        *(uint2*)&au[r * 264 + cc] = p1;
        *(uint2*)&as_[r * 264 + cc] = p2;
    }
    __syncthreads();

    int mrow0 = wv_ * 16;
    f32x4 gi[3][4], gh[3][4];
#pragma unroll
    for (int g3 = 0; g3 < 3; g3++)
#pragma unroll
        for (int nf = 0; nf < 4; nf++) {
            gi[g3][nf] = (f32x4){0.f, 0.f, 0.f, 0.f};
            gh[g3][nf] = (f32x4){0.f, 0.f, 0.f, 0.f};
        }
    for (int kk = 0; kk < 8; kk++) {
        bf16x8 a_u = *(const bf16x8*)&au[(mrow0 + l15) * 264 + kk * 32 + l4 * 8];
        bf16x8 a_s = *(const bf16x8*)&as_[(mrow0 + l15) * 264 + kk * 32 + l4 * 8];
#pragma unroll
        for (int g3 = 0; g3 < 3; g3++)
#pragma unroll
            for (int nf = 0; nf < 4; nf++) {
                int wrow = g3 * 256 + j0 + nf * 16 + l15;
                bf16x8 b1 = *(const bf16x8*)&Wih[wrow * 256 + kk * 32 + l4 * 8];
                bf16x8 b2 = *(const bf16x8*)&Whh[wrow * 256 + kk * 32 + l4 * 8];
                gi[g3][nf] = mfma16(a_u, b1, gi[g3][nf]);
                gh[g3][nf] = mfma16(a_s, b2, gh[g3][nf]);
            }
    }
#pragma unroll
    for (int nf = 0; nf < 4; nf++) {
        int col = j0 + nf * 16 + l15;
        float bir = bih[col], biz = bih[256 + col], bin_ = bih[512 + col];
        float bhr = bhh[col], bhz = bhh[256 + col], bhn = bhh[512 + col];
#pragma unroll
        for (int r = 0; r < 4; r++) {
            int row = m0 + mrow0 + l4 * 4 + r;
            float ir = gi[0][nf][r] + bir, iz = gi[1][nf][r] + biz, in_ = gi[2][nf][r] + bin_;
            float hr = gh[0][nf][r] + bhr, hz = gh[1][nf][r] + bhz, hn = gh[2][nf][r] + bhn;
            float rr = sigm(ir + hr);
            float zz = sigm(iz + hz);
            float nn = tanh_(in_ + rr * hn);
            float hp = slots[row * 256 + col];
            hout[row * 256 + col] = (1.f - zz) * nn + zz * hp;
        }
    }
}

// ---------------------------------------------------------------------------
// K6: MLP + residual: out = h + relu(LN(h)@W1^T + b1)@W2^T + b2
// ---------------------------------------------------------------------------
__global__ __launch_bounds__(256) void k_mlp(
    const float* __restrict__ h, const float* __restrict__ gln, const float* __restrict__ bln,
    const unsigned short* __restrict__ W1, const float* __restrict__ b1,
    const unsigned short* __restrict__ W2, const float* __restrict__ b2,
    float* __restrict__ outp)
{
    __shared__ unsigned short ms[32 * 264];
    __shared__ unsigned short fs[32 * 520];
    int t = threadIdx.x;
    int m0 = blockIdx.x * 32;
    int row = t >> 3, sg = t & 7;
    const float4* src = (const float4*)(h + (m0 + row) * 256 + sg * 32);
    float4 vv[8];
    float s = 0.f, ss = 0.f;
#pragma unroll
    for (int i = 0; i < 8; i++) {
        vv[i] = src[i];
        s  += vv[i].x + vv[i].y + vv[i].z + vv[i].w;
        ss += vv[i].x * vv[i].x + vv[i].y * vv[i].y + vv[i].z * vv[i].z + vv[i].w * vv[i].w;
    }
    s  += __shfl_xor(s, 1);  s  += __shfl_xor(s, 2);  s  += __shfl_xor(s, 4);
    ss += __shfl_xor(ss, 1); ss += __shfl_xor(ss, 2); ss += __shfl_xor(ss, 4);
    float mean = s * (1.f / 256.f);
    float rstd = rsqrtf(ss * (1.f / 256.f) - mean * mean + 1e-5f);
#pragma unroll
    for (int i = 0; i < 8; i++) {
        int c = sg * 32 + i * 4;
        float a0 = (vv[i].x - mean) * rstd * gln[c + 0] + bln[c + 0];
        float a1 = (vv[i].y - mean) * rstd * gln[c + 1] + bln[c + 1];
        float a2 = (vv[i].z - mean) * rstd * gln[c + 2] + bln[c + 2];
        float a3 = (vv[i].w - mean) * rstd * gln[c + 3] + bln[c + 3];
        uint2 pk; pk.x = pk2(a0, a1); pk.y = pk2(a2, a3);
        *(uint2*)&ms[row * 264 + c] = pk;
    }
    __syncthreads();

    int wv_ = t >> 6, l = t & 63, l15 = l & 15, l4 = l >> 4;
    // GEMM1: [32][512]
    f32x4 f1[2][8];
#pragma unroll
    for (int mf = 0; mf < 2; mf++)
#pragma unroll
        for (int nf = 0; nf < 8; nf++) f1[mf][nf] = (f32x4){0.f, 0.f, 0.f, 0.f};
    for (int kk = 0; kk < 8; kk++) {
        bf16x8 a0 = *(const bf16x8*)&ms[l15 * 264 + kk * 32 + l4 * 8];
        bf16x8 a1 = *(const bf16x8*)&ms[(16 + l15) * 264 + kk * 32 + l4 * 8];
#pragma unroll
        for (int nf = 0; nf < 8; nf++) {
            bf16x8 b = *(const bf16x8*)&W1[(wv_ * 128 + nf * 16 + l15) * 256 + kk * 32 + l4 * 8];
            f1[0][nf] = mfma16(a0, b, f1[0][nf]);
            f1[1][nf] = mfma16(a1, b, f1[1][nf]);
        }
    }
#pragma unroll
    for (int nf = 0; nf < 8; nf++) {
        int col = wv_ * 128 + nf * 16 + l15;
        float bb = b1[col];
#pragma unroll
        for (int mf = 0; mf < 2; mf++)
#pragma unroll
            for (int r = 0; r < 4; r++)
                fs[(mf * 16 + l4 * 4 + r) * 520 + col] = f2bf(fmaxf(f1[mf][nf][r] + bb, 0.f));
    }
    __syncthreads();

    // GEMM2: [32][256], K=512
    f32x4 o[2][4];
#pragma unroll
    for (int mf = 0; mf < 2; mf++)
#pragma unroll
        for (int nf = 0; nf < 4; nf++) o[mf][nf] = (f32x4){0.f, 0.f, 0.f, 0.f};
    for (int kk = 0; kk < 16; kk++) {
        bf16x8 a0 = *(const bf16x8*)&fs[l15 * 520 + kk * 32 + l4 * 8];
        bf16x8 a1 = *(const bf16x8*)&fs[(16 + l15) * 520 + kk * 32 + l4 * 8];
#pragma unroll
        for (int nf = 0; nf < 4; nf++) {
            bf16x8 b = *(const bf16x8*)&W2[(wv_ * 64 + nf * 16 + l15) * 512 + kk * 32 + l4 * 8];
            o[0][nf] = mfma16(a0, b, o[0][nf]);
            o[1][nf] = mfma16(a1, b, o[1][nf]);
        }
    }
#pragma unroll
    for (int nf = 0; nf < 4; nf++) {
        int col = wv_ * 64 + nf * 16 + l15;
        float bb = b2[col];
#pragma unroll
        for (int mf = 0; mf < 2; mf++)
#pragma unroll
            for (int r = 0; r < 4; r++) {
                int rw = m0 + mf * 16 + l4 * 4 + r;
                outp[rw * 256 + col] = o[mf][nf][r] + bb + h[rw * 256 + col];
            }
    }
}

// ---------------------------------------------------------------------------
extern "C" void kernel_launch(void* const* d_in, const int* in_sizes, int n_in,
                              void* d_out, int out_size, void* d_ws, size_t ws_size,
                              hipStream_t stream)
{
    const float* inputs   = (const float*)d_in[0];
    const float* noise    = (const float*)d_in[1];
    const float* mu       = (const float*)d_in[2];
    const float* sigma    = (const float*)d_in[3];
    const float* ln_in_g  = (const float*)d_in[4];
    const float* ln_in_b  = (const float*)d_in[5];
    const float* ln_s_g   = (const float*)d_in[6];
    const float* ln_s_b   = (const float*)d_in[7];
    const float* ln_m_g   = (const float*)d_in[8];
    const float* ln_m_b   = (const float*)d_in[9];
    const float* Wk       = (const float*)d_in[10];
    const float* bk       = (const float*)d_in[11];
    const float* Wv       = (const float*)d_in[12];
    const float* bv       = (const float*)d_in[13];
    const float* Wq       = (const float*)d_in[14];
    const float* bq       = (const float*)d_in[15];
    const float* W_ih     = (const float*)d_in[16];
    const float* W_hh     = (const float*)d_in[17];
    const float* b_ih     = (const float*)d_in[18];
    const float* b_hh     = (const float*)d_in[19];
    const float* W1       = (const float*)d_in[20];
    const float* b1       = (const float*)d_in[21];
    const float* W2       = (const float*)d_in[22];
    const float* b2       = (const float*)d_in[23];

    char* ws = (char*)d_ws;
    unsigned short* kbf  = (unsigned short*)(ws + 0);              // 67108864 B
    unsigned short* vTb  = (unsigned short*)(ws + 67108864);       // 67108864 B
    float*          slots= (float*)(ws + 134217728);               // 524288 B
    float*          hbuf = (float*)(ws + 134742016);               // 524288 B
    unsigned short* qbf  = (unsigned short*)(ws + 135266304);      // 262144 B
    float*          upd  = (float*)(ws + 135528448);               // 524288 B
    float*          part = (float*)(ws + 136052736);               // 8388608 B
    unsigned short* wkb  = (unsigned short*)(ws + 144441344);
    unsigned short* wvb  = (unsigned short*)(ws + 144572416);
    unsigned short* wqb  = (unsigned short*)(ws + 144703488);
    unsigned short* wihb = (unsigned short*)(ws + 144834560);
    unsigned short* whhb = (unsigned short*)(ws + 145227776);
    unsigned short* w1b  = (unsigned short*)(ws + 145620992);
    unsigned short* w2b  = (unsigned short*)(ws + 145883136);
    // total ws use: 146145280 B

    float* out_slots = (float*)d_out;
    float* out_attn  = out_slots + (MS * D_);   // 131072

    k_prep<<<3840, 256, 0, stream>>>(noise, mu, sigma, Wk, Wv, Wq, W_ih, W_hh, W1, W2,
                                     slots, wkb, wvb, wqb, wihb, whhb, w1b, w2b);
    k_lnkv<<<2048, 256, 0, stream>>>(inputs, ln_in_g, ln_in_b, wkb, wvb, bk, bv, kbf, vTb);

    for (int it = 0; it < 3; it++) {
        k_q<<<16, 256, 0, stream>>>(slots, ln_s_g, ln_s_b, wqb, bq, qbf);
        k_attn<<<512, 256, 0, stream>>>(kbf, vTb, qbf, out_attn, part);
        k_reduce<<<512, 256, 0, stream>>>(part, upd);
        k_gru<<<32, 256, 0, stream>>>(upd, slots, wihb, whhb, b_ih, b_hh, hbuf);
        k_mlp<<<16, 256, 0, stream>>>(hbuf, ln_m_g, ln_m_b, w1b, b1, w2b, b2,
                                      (it == 2) ? out_slots : slots);
    }
}

// Round 5
// 627.475 us; speedup vs baseline: 1.0743x; 1.0743x over previous
//
#include <hip/hip_runtime.h>
#include <stdint.h>

// Problem constants
#define B_  32
#define N_  4096
#define DIN 256
#define S_  16
#define D_  256
#define H_  512
#define MTOK (B_ * N_)   // 131072 token rows
#define MS   (B_ * S_)   // 512 slot rows

typedef __attribute__((ext_vector_type(8))) short bf16x8;
typedef __attribute__((ext_vector_type(4))) float f32x4;

__device__ __forceinline__ f32x4 mfma16(bf16x8 a, bf16x8 b, f32x4 c) {
    return __builtin_amdgcn_mfma_f32_16x16x32_bf16(a, b, c, 0, 0, 0);
}

__device__ __forceinline__ float bf2f(unsigned short u) {
    union { unsigned int i; float f; } c; c.i = ((unsigned int)u) << 16; return c.f;
}
__device__ __forceinline__ unsigned short f2bf(float f) {
    union { float f; unsigned int i; } c; c.f = f;
    unsigned int r = (c.i + 0x7fffu + ((c.i >> 16) & 1u)) >> 16;
    return (unsigned short)r;
}
__device__ __forceinline__ unsigned int pk2(float a, float b) {
    return (unsigned int)f2bf(a) | ((unsigned int)f2bf(b) << 16);
}
__device__ __forceinline__ float sigm(float x) { return 1.0f / (1.0f + __expf(-x)); }
__device__ __forceinline__ float tanh_(float x) {
    float e = __expf(-2.0f * fabsf(x));
    float t = (1.0f - e) / (1.0f + e);
    return copysignf(t, x);
}

// ---------------------------------------------------------------------------
// K0: slots init + fp32->bf16 weight conversion
// ---------------------------------------------------------------------------
__global__ __launch_bounds__(256) void k_prep(
    const float* __restrict__ noise, const float* __restrict__ mu, const float* __restrict__ sigma,
    const float* __restrict__ Wk, const float* __restrict__ Wv, const float* __restrict__ Wq,
    const float* __restrict__ Wih, const float* __restrict__ Whh,
    const float* __restrict__ W1, const float* __restrict__ W2,
    float* __restrict__ slots,
    unsigned short* __restrict__ wkb, unsigned short* __restrict__ wvb,
    unsigned short* __restrict__ wqb, unsigned short* __restrict__ wihb,
    unsigned short* __restrict__ whhb, unsigned short* __restrict__ w1b,
    unsigned short* __restrict__ w2b)
{
    int i = blockIdx.x * 256 + threadIdx.x;
    if (i < 131072) slots[i] = mu[i & 255] + sigma[i & 255] * noise[i];
    int j = i - 131072;
    if (j >= 0 && j < 65536) wkb[j] = f2bf(Wk[j]);
    j -= 65536;
    if (j >= 0 && j < 65536) wvb[j] = f2bf(Wv[j]);
    j -= 65536;
    if (j >= 0 && j < 65536) wqb[j] = f2bf(Wq[j]);
    j -= 65536;
    if (j >= 0 && j < 196608) wihb[j] = f2bf(Wih[j]);
    j -= 196608;
    if (j >= 0 && j < 196608) whhb[j] = f2bf(Whh[j]);
    j -= 196608;
    if (j >= 0 && j < 131072) w1b[j] = f2bf(W1[j]);
    j -= 131072;
    if (j >= 0 && j < 131072) w2b[j] = f2bf(W2[j]);
}

// ---------------------------------------------------------------------------
// K1 v2: fused LayerNorm(inputs) + k/v projections.
// 512 threads / 8 waves; per-wave tile 64 rows x 64 cols (acc[4][4] = 64 VGPR);
// waves 0-3 -> k cols 0-255, waves 4-7 -> v cols 0-255.
// LDS: single padded xa (264-stride) reused for LN output then C staging.
//   -> 35840 B LDS, <=128 VGPR (launch_bounds 512,4): target 16 waves/CU.
// ---------------------------------------------------------------------------
__global__ __launch_bounds__(512, 4) void k_lnkv(
    const float* __restrict__ inp, const float* __restrict__ gln, const float* __restrict__ bln,
    const unsigned short* __restrict__ Wk, const unsigned short* __restrict__ Wv,
    const float* __restrict__ bk, const float* __restrict__ bv,
    unsigned short* __restrict__ kout, unsigned short* __restrict__ vT)
{
    __shared__ unsigned short xa[64 * 264];   // 33792 B, padded row stride 528 B
    __shared__ float gl[256], bl[256];

    int t = threadIdx.x;
    long m0 = (long)blockIdx.x * 64;
    if (t < 256) { gl[t] = gln[t]; bl[t] = bln[t]; }

    // ---- LN stage: thread t handles row t>>3, eighth t&7 (32 floats) ----
    int row = t >> 3, seg = t & 7;
    const float4* src = (const float4*)(inp + (m0 + row) * 256 + seg * 32);
    float4 vv[8];
    float s = 0.f, ss = 0.f;
#pragma unroll
    for (int i = 0; i < 8; i++) {
        vv[i] = src[i];
        s  += vv[i].x + vv[i].y + vv[i].z + vv[i].w;
        ss += vv[i].x * vv[i].x + vv[i].y * vv[i].y + vv[i].z * vv[i].z + vv[i].w * vv[i].w;
    }
    s  += __shfl_xor(s, 1);  s  += __shfl_xor(s, 2);  s  += __shfl_xor(s, 4);
    ss += __shfl_xor(ss, 1); ss += __shfl_xor(ss, 2); ss += __shfl_xor(ss, 4);
    float mean = s * (1.f / 256.f);
    float rstd = rsqrtf(ss * (1.f / 256.f) - mean * mean + 1e-5f);
    __syncthreads();  // gl/bl ready
#pragma unroll
    for (int i = 0; i < 8; i++) {
        int c = seg * 32 + i * 4;
        float a0 = (vv[i].x - mean) * rstd * gl[c + 0] + bl[c + 0];
        float a1 = (vv[i].y - mean) * rstd * gl[c + 1] + bl[c + 1];
        float a2 = (vv[i].z - mean) * rstd * gl[c + 2] + bl[c + 2];
        float a3 = (vv[i].w - mean) * rstd * gl[c + 3] + bl[c + 3];
        uint2 pk; pk.x = pk2(a0, a1); pk.y = pk2(a2, a3);
        *(uint2*)&xa[row * 264 + c] = pk;
    }
    __syncthreads();

    // ---- GEMM: wave w (<4: k, >=4: v), cols ncol0..ncol0+63 ----
    int wv_ = t >> 6, l = t & 63, l15 = l & 15, l4 = l >> 4;
    const unsigned short* Wsel = (wv_ < 4) ? Wk : Wv;
    int ncol0 = (wv_ & 3) * 64;
    f32x4 acc[4][4];
#pragma unroll
    for (int mf = 0; mf < 4; mf++)
#pragma unroll
        for (int nf = 0; nf < 4; nf++) acc[mf][nf] = (f32x4){0.f, 0.f, 0.f, 0.f};

    for (int kk = 0; kk < 8; kk++) {
        bf16x8 a[4];
#pragma unroll
        for (int mf = 0; mf < 4; mf++)
            a[mf] = *(const bf16x8*)&xa[(mf * 16 + l15) * 264 + kk * 32 + l4 * 8];
#pragma unroll
        for (int nf = 0; nf < 4; nf++) {
            bf16x8 b = *(const bf16x8*)&Wsel[(ncol0 + nf * 16 + l15) * 256 + kk * 32 + l4 * 8];
#pragma unroll
            for (int mf = 0; mf < 4; mf++) acc[mf][nf] = mfma16(a[mf], b, acc[mf][nf]);
        }
    }
    __syncthreads();  // xa dead; reuse for C staging

    // ---- k stage (waves 0-3) into padded xa ----
    if (wv_ < 4) {
#pragma unroll
        for (int nf = 0; nf < 4; nf++) {
            int col = ncol0 + nf * 16 + l15;
            float bias = bk[col];
#pragma unroll
            for (int mf = 0; mf < 4; mf++)
#pragma unroll
                for (int r = 0; r < 4; r++)
                    xa[(mf * 16 + l4 * 4 + r) * 264 + col] = f2bf(acc[mf][nf][r] + bias);
        }
    }
    __syncthreads();
    {   // flat coalesced k write
        uint4* d4 = (uint4*)(kout + m0 * 256);
        for (int c = t; c < 2048; c += 512) {
            int rr = c >> 5;
            d4[c] = *(const uint4*)&xa[rr * 264 + (c & 31) * 8];
        }
    }
    __syncthreads();
    // ---- v stage (waves 4-7) ----
    if (wv_ >= 4) {
#pragma unroll
        for (int nf = 0; nf < 4; nf++) {
            int col = ncol0 + nf * 16 + l15;
            float bias = bv[col];
#pragma unroll
            for (int mf = 0; mf < 4; mf++)
#pragma unroll
                for (int r = 0; r < 4; r++)
                    xa[(mf * 16 + l4 * 4 + r) * 264 + col] = f2bf(acc[mf][nf][r] + bias);
        }
    }
    __syncthreads();
    {   // transposed write: vT[b][d][tok]; thread (th, d) covers 32 tokens
        int th = t >> 8;           // 0/1: token half
        int d  = t & 255;
        int bb = (int)(m0 >> 12);
        int tok0 = (int)(m0 & 4095);
        unsigned short tmp[32];
#pragma unroll
        for (int i = 0; i < 32; i++) tmp[i] = xa[(th * 32 + i) * 264 + d];
        uint4* dst = (uint4*)(vT + ((long)bb * 256 + d) * 4096 + tok0 + th * 32);
#pragma unroll
        for (int c = 0; c < 4; c++) dst[c] = ((const uint4*)tmp)[c];
    }
}

// ---------------------------------------------------------------------------
// K2: q = LN(slots)@Wq^T + bq  -> q_bf16 [512][256]
// ---------------------------------------------------------------------------
__global__ __launch_bounds__(256) void k_q(
    const float* __restrict__ slots, const float* __restrict__ gln, const float* __restrict__ bln,
    const unsigned short* __restrict__ Wq, const float* __restrict__ bq,
    unsigned short* __restrict__ qout)
{
    __shared__ unsigned short ms[32 * 264];
    int t = threadIdx.x;
    int m0 = blockIdx.x * 32;
    int row = t >> 3, sg = t & 7;
    const float4* src = (const float4*)(slots + (m0 + row) * 256 + sg * 32);
    float4 vv[8];
    float s = 0.f, ss = 0.f;
#pragma unroll
    for (int i = 0; i < 8; i++) {
        vv[i] = src[i];
        s  += vv[i].x + vv[i].y + vv[i].z + vv[i].w;
        ss += vv[i].x * vv[i].x + vv[i].y * vv[i].y + vv[i].z * vv[i].z + vv[i].w * vv[i].w;
    }
    s  += __shfl_xor(s, 1);  s  += __shfl_xor(s, 2);  s  += __shfl_xor(s, 4);
    ss += __shfl_xor(ss, 1); ss += __shfl_xor(ss, 2); ss += __shfl_xor(ss, 4);
    float mean = s * (1.f / 256.f);
    float rstd = rsqrtf(ss * (1.f / 256.f) - mean * mean + 1e-5f);
#pragma unroll
    for (int i = 0; i < 8; i++) {
        int c = sg * 32 + i * 4;
        float a0 = (vv[i].x - mean) * rstd * gln[c + 0] + bln[c + 0];
        float a1 = (vv[i].y - mean) * rstd * gln[c + 1] + bln[c + 1];
        float a2 = (vv[i].z - mean) * rstd * gln[c + 2] + bln[c + 2];
        float a3 = (vv[i].w - mean) * rstd * gln[c + 3] + bln[c + 3];
        uint2 pk; pk.x = pk2(a0, a1); pk.y = pk2(a2, a3);
        *(uint2*)&ms[row * 264 + c] = pk;
    }
    __syncthreads();

    int wv_ = t >> 6, l = t & 63, l15 = l & 15, l4 = l >> 4;
    f32x4 o[2][4];
#pragma unroll
    for (int mf = 0; mf < 2; mf++)
#pragma unroll
        for (int nf = 0; nf < 4; nf++) o[mf][nf] = (f32x4){0.f, 0.f, 0.f, 0.f};
    for (int kk = 0; kk < 8; kk++) {
        bf16x8 a0 = *(const bf16x8*)&ms[l15 * 264 + kk * 32 + l4 * 8];
        bf16x8 a1 = *(const bf16x8*)&ms[(16 + l15) * 264 + kk * 32 + l4 * 8];
#pragma unroll
        for (int nf = 0; nf < 4; nf++) {
            bf16x8 b = *(const bf16x8*)&Wq[(wv_ * 64 + nf * 16 + l15) * 256 + kk * 32 + l4 * 8];
            o[0][nf] = mfma16(a0, b, o[0][nf]);
            o[1][nf] = mfma16(a1, b, o[1][nf]);
        }
    }
#pragma unroll
    for (int nf = 0; nf < 4; nf++) {
        int col = wv_ * 64 + nf * 16 + l15;
        float bb = bq[col];
#pragma unroll
        for (int mf = 0; mf < 2; mf++)
#pragma unroll
            for (int r = 0; r < 4; r++)
                qout[(m0 + mf * 16 + l4 * 4 + r) * 256 + col] = f2bf(o[mf][nf][r] + bb);
    }
}

// ---------------------------------------------------------------------------
// K3: fused attention pass for one (b, 256-token chunk):
//     logits -> softmax over S (in-fragment shuffle) -> attn (fp32 out)
//     -> partial updates = attn @ v accumulated via fp32 atomicAdd into upd
// ---------------------------------------------------------------------------
__global__ __launch_bounds__(256) void k_attn(
    const unsigned short* __restrict__ kbf, const unsigned short* __restrict__ vT,
    const unsigned short* __restrict__ qbf, float* __restrict__ attn_out,
    float* __restrict__ upd)
{
    __shared__ unsigned short qs[16 * 264];
    __shared__ unsigned short as_[16 * 264];
    int t = threadIdx.x, l = t & 63, wv_ = t >> 6, l15 = l & 15, l4 = l >> 4;
    int b = blockIdx.x >> 4;
    int chunk = blockIdx.x & 15;
    int tok_base = chunk * 256;

    for (int c = t; c < 512; c += 256) {
        int r = c >> 5, cc = c & 31;
        *(uint4*)&qs[r * 264 + cc * 8] = *(const uint4*)&qbf[(b * 16 + r) * 256 + cc * 8];
    }
    __syncthreads();

    // ---- phase A: logits + softmax over slots ----
    int wtok = tok_base + wv_ * 64;
#pragma unroll
    for (int tf = 0; tf < 4; tf++) {
        int tok0 = wtok + tf * 16;
        f32x4 c4 = (f32x4){0.f, 0.f, 0.f, 0.f};
        const unsigned short* krow = kbf + ((long)b * 4096 + tok0 + l15) * 256 + l4 * 8;
#pragma unroll
        for (int kk = 0; kk < 8; kk++) {
            bf16x8 a = *(const bf16x8*)&qs[l15 * 264 + kk * 32 + l4 * 8];
            bf16x8 bb = *(const bf16x8*)&krow[kk * 32];
            c4 = mfma16(a, bb, c4);
        }
#pragma unroll
        for (int r = 0; r < 4; r++) c4[r] *= 0.0625f;   // D^-0.5
        float mx = fmaxf(fmaxf(c4[0], c4[1]), fmaxf(c4[2], c4[3]));
        mx = fmaxf(mx, __shfl_xor(mx, 16));
        mx = fmaxf(mx, __shfl_xor(mx, 32));
        float e[4]; float sm = 0.f;
#pragma unroll
        for (int r = 0; r < 4; r++) { e[r] = __expf(c4[r] - mx); sm += e[r]; }
        sm += __shfl_xor(sm, 16);
        sm += __shfl_xor(sm, 32);
        float inv = 1.0f / sm;
#pragma unroll
        for (int r = 0; r < 4; r++) {
            float av = e[r] * inv;
            int srow = l4 * 4 + r;
            attn_out[((long)b * 16 + srow) * 4096 + tok0 + l15] = av;
            as_[srow * 264 + wv_ * 64 + tf * 16 + l15] = f2bf(av);
        }
    }
    __syncthreads();

    // ---- phase B: partial updates = attn[16 x 256] @ v[256 x 256] ----
    int d0 = wv_ * 64;
    f32x4 u[4];
#pragma unroll
    for (int df = 0; df < 4; df++) u[df] = (f32x4){0.f, 0.f, 0.f, 0.f};
    for (int kk = 0; kk < 8; kk++) {
        bf16x8 a = *(const bf16x8*)&as_[l15 * 264 + kk * 32 + l4 * 8];
#pragma unroll
        for (int df = 0; df < 4; df++) {
            bf16x8 bb = *(const bf16x8*)&vT[((long)b * 256 + d0 + df * 16 + l15) * 4096
                                            + tok_base + kk * 32 + l4 * 8];
            u[df] = mfma16(a, bb, u[df]);
        }
    }
#pragma unroll
    for (int df = 0; df < 4; df++)
#pragma unroll
        for (int r = 0; r < 4; r++) {
            int srow = l4 * 4 + r;
            atomicAdd(&upd[(b * 16 + srow) * 256 + d0 + df * 16 + l15], u[df][r]);
        }
}

// ---------------------------------------------------------------------------
// K5: GRU cell: h = GRUCell(updates, slots)
// tile [64 m][64 j], 3 gate column-groups x {W_ih, W_hh}
// ---------------------------------------------------------------------------
__global__ __launch_bounds__(256) void k_gru(
    const float* __restrict__ upd, const float* __restrict__ slots,
    const unsigned short* __restrict__ Wih, const unsigned short* __restrict__ Whh,
    const float* __restrict__ bih, const float* __restrict__ bhh,
    float* __restrict__ hout)
{
    __shared__ unsigned short au[64 * 264], as_[64 * 264];
    int t = threadIdx.x, l = t & 63, wv_ = t >> 6, l15 = l & 15, l4 = l >> 4;
    int m0 = (blockIdx.x >> 2) * 64;
    int j0 = (blockIdx.x & 3) * 64;

    for (int c = t; c < 4096; c += 256) {
        int r = c >> 6, cc = (c & 63) * 4;
        float4 v1 = *(const float4*)&upd[(m0 + r) * 256 + cc];
        float4 v2 = *(const float4*)&slots[(m0 + r) * 256 + cc];
        uint2 p1; p1.x = pk2(v1.x, v1.y); p1.y = pk2(v1.z, v1.w);
        uint2 p2; p2.x = pk2(v2.x, v2.y); p2.y = pk2(v2.z, v2.w);
        *(uint2*)&au[r * 264 + cc] = p1;
        *(uint2*)&as_[r * 264 + cc] = p2;
    }
    __syncthreads();

    int mrow0 = wv_ * 16;
    f32x4 gi[3][4], gh[3][4];
#pragma unroll
    for (int g3 = 0; g3 < 3; g3++)
#pragma unroll
        for (int nf = 0; nf < 4; nf++) {
            gi[g3][nf] = (f32x4){0.f, 0.f, 0.f, 0.f};
            gh[g3][nf] = (f32x4){0.f, 0.f, 0.f, 0.f};
        }
    for (int kk = 0; kk < 8; kk++) {
        bf16x8 a_u = *(const bf16x8*)&au[(mrow0 + l15) * 264 + kk * 32 + l4 * 8];
        bf16x8 a_s = *(const bf16x8*)&as_[(mrow0 + l15) * 264 + kk * 32 + l4 * 8];
#pragma unroll
        for (int g3 = 0; g3 < 3; g3++)
#pragma unroll
            for (int nf = 0; nf < 4; nf++) {
                int wrow = g3 * 256 + j0 + nf * 16 + l15;
                bf16x8 b1 = *(const bf16x8*)&Wih[wrow * 256 + kk * 32 + l4 * 8];
                bf16x8 b2 = *(const bf16x8*)&Whh[wrow * 256 + kk * 32 + l4 * 8];
                gi[g3][nf] = mfma16(a_u, b1, gi[g3][nf]);
                gh[g3][nf] = mfma16(a_s, b2, gh[g3][nf]);
            }
    }
#pragma unroll
    for (int nf = 0; nf < 4; nf++) {
        int col = j0 + nf * 16 + l15;
        float bir = bih[col], biz = bih[256 + col], bin_ = bih[512 + col];
        float bhr = bhh[col], bhz = bhh[256 + col], bhn = bhh[512 + col];
#pragma unroll
        for (int r = 0; r < 4; r++) {
            int row = m0 + mrow0 + l4 * 4 + r;
            float ir = gi[0][nf][r] + bir, iz = gi[1][nf][r] + biz, in_ = gi[2][nf][r] + bin_;
            float hr = gh[0][nf][r] + bhr, hz = gh[1][nf][r] + bhz, hn = gh[2][nf][r] + bhn;
            float rr = sigm(ir + hr);
            float zz = sigm(iz + hz);
            float nn = tanh_(in_ + rr * hn);
            float hp = slots[row * 256 + col];
            hout[row * 256 + col] = (1.f - zz) * nn + zz * hp;
        }
    }
}

// ---------------------------------------------------------------------------
// K6: MLP + residual: out = h + relu(LN(h)@W1^T + b1)@W2^T + b2
// ---------------------------------------------------------------------------
__global__ __launch_bounds__(256) void k_mlp(
    const float* __restrict__ h, const float* __restrict__ gln, const float* __restrict__ bln,
    const unsigned short* __restrict__ W1, const float* __restrict__ b1,
    const unsigned short* __restrict__ W2, const float* __restrict__ b2,
    float* __restrict__ outp)
{
    __shared__ unsigned short ms[32 * 264];
    __shared__ unsigned short fs[32 * 520];
    int t = threadIdx.x;
    int m0 = blockIdx.x * 32;
    int row = t >> 3, sg = t & 7;
    const float4* src = (const float4*)(h + (m0 + row) * 256 + sg * 32);
    float4 vv[8];
    float s = 0.f, ss = 0.f;
#pragma unroll
    for (int i = 0; i < 8; i++) {
        vv[i] = src[i];
        s  += vv[i].x + vv[i].y + vv[i].z + vv[i].w;
        ss += vv[i].x * vv[i].x + vv[i].y * vv[i].y + vv[i].z * vv[i].z + vv[i].w * vv[i].w;
    }
    s  += __shfl_xor(s, 1);  s  += __shfl_xor(s, 2);  s  += __shfl_xor(s, 4);
    ss += __shfl_xor(ss, 1); ss += __shfl_xor(ss, 2); ss += __shfl_xor(ss, 4);
    float mean = s * (1.f / 256.f);
    float rstd = rsqrtf(ss * (1.f / 256.f) - mean * mean + 1e-5f);
#pragma unroll
    for (int i = 0; i < 8; i++) {
        int c = sg * 32 + i * 4;
        float a0 = (vv[i].x - mean) * rstd * gln[c + 0] + bln[c + 0];
        float a1 = (vv[i].y - mean) * rstd * gln[c + 1] + bln[c + 1];
        float a2 = (vv[i].z - mean) * rstd * gln[c + 2] + bln[c + 2];
        float a3 = (vv[i].w - mean) * rstd * gln[c + 3] + bln[c + 3];
        uint2 pk; pk.x = pk2(a0, a1); pk.y = pk2(a2, a3);
        *(uint2*)&ms[row * 264 + c] = pk;
    }
    __syncthreads();

    int wv_ = t >> 6, l = t & 63, l15 = l & 15, l4 = l >> 4;
    // GEMM1: [32][512]
    f32x4 f1[2][8];
#pragma unroll
    for (int mf = 0; mf < 2; mf++)
#pragma unroll
        for (int nf = 0; nf < 8; nf++) f1[mf][nf] = (f32x4){0.f, 0.f, 0.f, 0.f};
    for (int kk = 0; kk < 8; kk++) {
        bf16x8 a0 = *(const bf16x8*)&ms[l15 * 264 + kk * 32 + l4 * 8];
        bf16x8 a1 = *(const bf16x8*)&ms[(16 + l15) * 264 + kk * 32 + l4 * 8];
#pragma unroll
        for (int nf = 0; nf < 8; nf++) {
            bf16x8 b = *(const bf16x8*)&W1[(wv_ * 128 + nf * 16 + l15) * 256 + kk * 32 + l4 * 8];
            f1[0][nf] = mfma16(a0, b, f1[0][nf]);
            f1[1][nf] = mfma16(a1, b, f1[1][nf]);
        }
    }
#pragma unroll
    for (int nf = 0; nf < 8; nf++) {
        int col = wv_ * 128 + nf * 16 + l15;
        float bb = b1[col];
#pragma unroll
        for (int mf = 0; mf < 2; mf++)
#pragma unroll
            for (int r = 0; r < 4; r++)
                fs[(mf * 16 + l4 * 4 + r) * 520 + col] = f2bf(fmaxf(f1[mf][nf][r] + bb, 0.f));
    }
    __syncthreads();

    // GEMM2: [32][256], K=512
    f32x4 o[2][4];
#pragma unroll
    for (int mf = 0; mf < 2; mf++)
#pragma unroll
        for (int nf = 0; nf < 4; nf++) o[mf][nf] = (f32x4){0.f, 0.f, 0.f, 0.f};
    for (int kk = 0; kk < 16; kk++) {
        bf16x8 a0 = *(const bf16x8*)&fs[l15 * 520 + kk * 32 + l4 * 8];
        bf16x8 a1 = *(const bf16x8*)&fs[(16 + l15) * 520 + kk * 32 + l4 * 8];
#pragma unroll
        for (int nf = 0; nf < 4; nf++) {
            bf16x8 b = *(const bf16x8*)&W2[(wv_ * 64 + nf * 16 + l15) * 512 + kk * 32 + l4 * 8];
            o[0][nf] = mfma16(a0, b, o[0][nf]);
            o[1][nf] = mfma16(a1, b, o[1][nf]);
        }
    }
#pragma unroll
    for (int nf = 0; nf < 4; nf++) {
        int col = wv_ * 64 + nf * 16 + l15;
        float bb = b2[col];
#pragma unroll
        for (int mf = 0; mf < 2; mf++)
#pragma unroll
            for (int r = 0; r < 4; r++) {
                int rw = m0 + mf * 16 + l4 * 4 + r;
                outp[rw * 256 + col] = o[mf][nf][r] + bb + h[rw * 256 + col];
            }
    }
}

// ---------------------------------------------------------------------------
extern "C" void kernel_launch(void* const* d_in, const int* in_sizes, int n_in,
                              void* d_out, int out_size, void* d_ws, size_t ws_size,
                              hipStream_t stream)
{
    const float* inputs   = (const float*)d_in[0];
    const float* noise    = (const float*)d_in[1];
    const float* mu       = (const float*)d_in[2];
    const float* sigma    = (const float*)d_in[3];
    const float* ln_in_g  = (const float*)d_in[4];
    const float* ln_in_b  = (const float*)d_in[5];
    const float* ln_s_g   = (const float*)d_in[6];
    const float* ln_s_b   = (const float*)d_in[7];
    const float* ln_m_g   = (const float*)d_in[8];
    const float* ln_m_b   = (const float*)d_in[9];
    const float* Wk       = (const float*)d_in[10];
    const float* bk       = (const float*)d_in[11];
    const float* Wv       = (const float*)d_in[12];
    const float* bv       = (const float*)d_in[13];
    const float* Wq       = (const float*)d_in[14];
    const float* bq       = (const float*)d_in[15];
    const float* W_ih     = (const float*)d_in[16];
    const float* W_hh     = (const float*)d_in[17];
    const float* b_ih     = (const float*)d_in[18];
    const float* b_hh     = (const float*)d_in[19];
    const float* W1       = (const float*)d_in[20];
    const float* b1       = (const float*)d_in[21];
    const float* W2       = (const float*)d_in[22];
    const float* b2       = (const float*)d_in[23];

    char* ws = (char*)d_ws;
    unsigned short* kbf  = (unsigned short*)(ws + 0);              // 67108864 B
    unsigned short* vTb  = (unsigned short*)(ws + 67108864);       // 67108864 B
    float*          slots= (float*)(ws + 134217728);               // 524288 B
    float*          hbuf = (float*)(ws + 134742016);               // 524288 B
    unsigned short* qbf  = (unsigned short*)(ws + 135266304);      // 262144 B
    float*          upd  = (float*)(ws + 135528448);               // 524288 B
    unsigned short* wkb  = (unsigned short*)(ws + 144441344);
    unsigned short* wvb  = (unsigned short*)(ws + 144572416);
    unsigned short* wqb  = (unsigned short*)(ws + 144703488);
    unsigned short* wihb = (unsigned short*)(ws + 144834560);
    unsigned short* whhb = (unsigned short*)(ws + 145227776);
    unsigned short* w1b  = (unsigned short*)(ws + 145620992);
    unsigned short* w2b  = (unsigned short*)(ws + 145883136);
    // total ws use: 146145280 B

    float* out_slots = (float*)d_out;
    float* out_attn  = out_slots + (MS * D_);   // 131072

    k_prep<<<3840, 256, 0, stream>>>(noise, mu, sigma, Wk, Wv, Wq, W_ih, W_hh, W1, W2,
                                     slots, wkb, wvb, wqb, wihb, whhb, w1b, w2b);
    k_lnkv<<<2048, 512, 0, stream>>>(inputs, ln_in_g, ln_in_b, wkb, wvb, bk, bv, kbf, vTb);

    for (int it = 0; it < 3; it++) {
        k_q<<<16, 256, 0, stream>>>(slots, ln_s_g, ln_s_b, wqb, bq, qbf);
        hipMemsetAsync(upd, 0, MS * D_ * sizeof(float), stream);
        k_attn<<<512, 256, 0, stream>>>(kbf, vTb, qbf, out_attn, upd);
        k_gru<<<32, 256, 0, stream>>>(upd, slots, wihb, whhb, b_ih, b_hh, hbuf);
        k_mlp<<<16, 256, 0, stream>>>(hbuf, ln_m_g, ln_m_b, w1b, b1, w2b, b2,
                                      (it == 2) ? out_slots : slots);
    }
}

// Round 6
// 624.990 us; speedup vs baseline: 1.0785x; 1.0040x over previous
//
#include <hip/hip_runtime.h>
#include <stdint.h>

// Problem constants
#define B_  32
#define N_  4096
#define DIN 256
#define S_  16
#define D_  256
#define H_  512
#define MTOK (B_ * N_)   // 131072 token rows
#define MS   (B_ * S_)   // 512 slot rows

typedef __attribute__((ext_vector_type(8))) short bf16x8;
typedef __attribute__((ext_vector_type(4))) float f32x4;

__device__ __forceinline__ f32x4 mfma16(bf16x8 a, bf16x8 b, f32x4 c) {
    return __builtin_amdgcn_mfma_f32_16x16x32_bf16(a, b, c, 0, 0, 0);
}

__device__ __forceinline__ float bf2f(unsigned short u) {
    union { unsigned int i; float f; } c; c.i = ((unsigned int)u) << 16; return c.f;
}
__device__ __forceinline__ unsigned short f2bf(float f) {
    union { float f; unsigned int i; } c; c.f = f;
    unsigned int r = (c.i + 0x7fffu + ((c.i >> 16) & 1u)) >> 16;
    return (unsigned short)r;
}
__device__ __forceinline__ unsigned int pk2(float a, float b) {
    return (unsigned int)f2bf(a) | ((unsigned int)f2bf(b) << 16);
}
__device__ __forceinline__ float sigm(float x) { return 1.0f / (1.0f + __expf(-x)); }
__device__ __forceinline__ float tanh_(float x) {
    float e = __expf(-2.0f * fabsf(x));
    float t = (1.0f - e) / (1.0f + e);
    return copysignf(t, x);
}

// ---------------------------------------------------------------------------
// K0: slots init + fp32->bf16 weight conversion
// ---------------------------------------------------------------------------
__global__ __launch_bounds__(256) void k_prep(
    const float* __restrict__ noise, const float* __restrict__ mu, const float* __restrict__ sigma,
    const float* __restrict__ Wk, const float* __restrict__ Wv, const float* __restrict__ Wq,
    const float* __restrict__ Wih, const float* __restrict__ Whh,
    const float* __restrict__ W1, const float* __restrict__ W2,
    float* __restrict__ slots,
    unsigned short* __restrict__ wkb, unsigned short* __restrict__ wvb,
    unsigned short* __restrict__ wqb, unsigned short* __restrict__ wihb,
    unsigned short* __restrict__ whhb, unsigned short* __restrict__ w1b,
    unsigned short* __restrict__ w2b)
{
    int i = blockIdx.x * 256 + threadIdx.x;
    if (i < 131072) slots[i] = mu[i & 255] + sigma[i & 255] * noise[i];
    int j = i - 131072;
    if (j >= 0 && j < 65536) wkb[j] = f2bf(Wk[j]);
    j -= 65536;
    if (j >= 0 && j < 65536) wvb[j] = f2bf(Wv[j]);
    j -= 65536;
    if (j >= 0 && j < 65536) wqb[j] = f2bf(Wq[j]);
    j -= 65536;
    if (j >= 0 && j < 196608) wihb[j] = f2bf(Wih[j]);
    j -= 196608;
    if (j >= 0 && j < 196608) whhb[j] = f2bf(Whh[j]);
    j -= 196608;
    if (j >= 0 && j < 131072) w1b[j] = f2bf(W1[j]);
    j -= 131072;
    if (j >= 0 && j < 131072) w2b[j] = f2bf(W2[j]);
}

// ---------------------------------------------------------------------------
// K1 v3: fused LayerNorm(inputs) + k/v projections.
// 512 threads / 8 waves; per-wave tile 64 rows x 64 cols (acc[4][4]);
// GEMM kk loop fully unrolled so all weight loads issue before the MFMAs
// (round-5 profile: all pipes <20% busy at 42% occupancy = exposed latency).
// ---------------------------------------------------------------------------
__global__ __launch_bounds__(512, 4) void k_lnkv(
    const float* __restrict__ inp, const float* __restrict__ gln, const float* __restrict__ bln,
    const unsigned short* __restrict__ Wk, const unsigned short* __restrict__ Wv,
    const float* __restrict__ bk, const float* __restrict__ bv,
    unsigned short* __restrict__ kout, unsigned short* __restrict__ vT)
{
    __shared__ unsigned short xa[64 * 264];   // 33792 B, padded row stride 528 B
    __shared__ float gl[256], bl[256];

    int t = threadIdx.x;
    long m0 = (long)blockIdx.x * 64;
    if (t < 256) { gl[t] = gln[t]; bl[t] = bln[t]; }

    // ---- LN stage: thread t handles row t>>3, eighth t&7 (32 floats) ----
    int row = t >> 3, seg = t & 7;
    const float4* src = (const float4*)(inp + (m0 + row) * 256 + seg * 32);
    float4 vv[8];
    float s = 0.f, ss = 0.f;
#pragma unroll
    for (int i = 0; i < 8; i++) {
        vv[i] = src[i];
        s  += vv[i].x + vv[i].y + vv[i].z + vv[i].w;
        ss += vv[i].x * vv[i].x + vv[i].y * vv[i].y + vv[i].z * vv[i].z + vv[i].w * vv[i].w;
    }
    s  += __shfl_xor(s, 1);  s  += __shfl_xor(s, 2);  s  += __shfl_xor(s, 4);
    ss += __shfl_xor(ss, 1); ss += __shfl_xor(ss, 2); ss += __shfl_xor(ss, 4);
    float mean = s * (1.f / 256.f);
    float rstd = rsqrtf(ss * (1.f / 256.f) - mean * mean + 1e-5f);
    __syncthreads();  // gl/bl ready
#pragma unroll
    for (int i = 0; i < 8; i++) {
        int c = seg * 32 + i * 4;
        float a0 = (vv[i].x - mean) * rstd * gl[c + 0] + bl[c + 0];
        float a1 = (vv[i].y - mean) * rstd * gl[c + 1] + bl[c + 1];
        float a2 = (vv[i].z - mean) * rstd * gl[c + 2] + bl[c + 2];
        float a3 = (vv[i].w - mean) * rstd * gl[c + 3] + bl[c + 3];
        uint2 pk; pk.x = pk2(a0, a1); pk.y = pk2(a2, a3);
        *(uint2*)&xa[row * 264 + c] = pk;
    }
    __syncthreads();

    // ---- GEMM: wave w (<4: k, >=4: v), cols ncol0..ncol0+63 ----
    int wv_ = t >> 6, l = t & 63, l15 = l & 15, l4 = l >> 4;
    const unsigned short* Wsel = (wv_ < 4) ? Wk : Wv;
    int ncol0 = (wv_ & 3) * 64;
    f32x4 acc[4][4];
#pragma unroll
    for (int mf = 0; mf < 4; mf++)
#pragma unroll
        for (int nf = 0; nf < 4; nf++) acc[mf][nf] = (f32x4){0.f, 0.f, 0.f, 0.f};

#pragma unroll
    for (int kk = 0; kk < 8; kk++) {
        bf16x8 a[4];
#pragma unroll
        for (int mf = 0; mf < 4; mf++)
            a[mf] = *(const bf16x8*)&xa[(mf * 16 + l15) * 264 + kk * 32 + l4 * 8];
#pragma unroll
        for (int nf = 0; nf < 4; nf++) {
            bf16x8 b = *(const bf16x8*)&Wsel[(ncol0 + nf * 16 + l15) * 256 + kk * 32 + l4 * 8];
#pragma unroll
            for (int mf = 0; mf < 4; mf++) acc[mf][nf] = mfma16(a[mf], b, acc[mf][nf]);
        }
    }
    __syncthreads();  // xa dead; reuse for C staging

    // ---- k stage (waves 0-3) into padded xa ----
    if (wv_ < 4) {
#pragma unroll
        for (int nf = 0; nf < 4; nf++) {
            int col = ncol0 + nf * 16 + l15;
            float bias = bk[col];
#pragma unroll
            for (int mf = 0; mf < 4; mf++)
#pragma unroll
                for (int r = 0; r < 4; r++)
                    xa[(mf * 16 + l4 * 4 + r) * 264 + col] = f2bf(acc[mf][nf][r] + bias);
        }
    }
    __syncthreads();
    {   // flat coalesced k write
        uint4* d4 = (uint4*)(kout + m0 * 256);
        for (int c = t; c < 2048; c += 512) {
            int rr = c >> 5;
            d4[c] = *(const uint4*)&xa[rr * 264 + (c & 31) * 8];
        }
    }
    __syncthreads();
    // ---- v stage (waves 4-7) ----
    if (wv_ >= 4) {
#pragma unroll
        for (int nf = 0; nf < 4; nf++) {
            int col = ncol0 + nf * 16 + l15;
            float bias = bv[col];
#pragma unroll
            for (int mf = 0; mf < 4; mf++)
#pragma unroll
                for (int r = 0; r < 4; r++)
                    xa[(mf * 16 + l4 * 4 + r) * 264 + col] = f2bf(acc[mf][nf][r] + bias);
        }
    }
    __syncthreads();
    {   // transposed write: vT[b][d][tok]; thread (th, d) covers 32 tokens
        int th = t >> 8;           // 0/1: token half
        int d  = t & 255;
        int bb = (int)(m0 >> 12);
        int tok0 = (int)(m0 & 4095);
        unsigned short tmp[32];
#pragma unroll
        for (int i = 0; i < 32; i++) tmp[i] = xa[(th * 32 + i) * 264 + d];
        uint4* dst = (uint4*)(vT + ((long)bb * 256 + d) * 4096 + tok0 + th * 32);
#pragma unroll
        for (int c = 0; c < 4; c++) dst[c] = ((const uint4*)tmp)[c];
    }
}

// ---------------------------------------------------------------------------
// K2: q = LN(slots)@Wq^T + bq  -> q_bf16 [512][256]
// ---------------------------------------------------------------------------
__global__ __launch_bounds__(256) void k_q(
    const float* __restrict__ slots, const float* __restrict__ gln, const float* __restrict__ bln,
    const unsigned short* __restrict__ Wq, const float* __restrict__ bq,
    unsigned short* __restrict__ qout)
{
    __shared__ unsigned short ms[32 * 264];
    int t = threadIdx.x;
    int m0 = blockIdx.x * 32;
    int row = t >> 3, sg = t & 7;
    const float4* src = (const float4*)(slots + (m0 + row) * 256 + sg * 32);
    float4 vv[8];
    float s = 0.f, ss = 0.f;
#pragma unroll
    for (int i = 0; i < 8; i++) {
        vv[i] = src[i];
        s  += vv[i].x + vv[i].y + vv[i].z + vv[i].w;
        ss += vv[i].x * vv[i].x + vv[i].y * vv[i].y + vv[i].z * vv[i].z + vv[i].w * vv[i].w;
    }
    s  += __shfl_xor(s, 1);  s  += __shfl_xor(s, 2);  s  += __shfl_xor(s, 4);
    ss += __shfl_xor(ss, 1); ss += __shfl_xor(ss, 2); ss += __shfl_xor(ss, 4);
    float mean = s * (1.f / 256.f);
    float rstd = rsqrtf(ss * (1.f / 256.f) - mean * mean + 1e-5f);
#pragma unroll
    for (int i = 0; i < 8; i++) {
        int c = sg * 32 + i * 4;
        float a0 = (vv[i].x - mean) * rstd * gln[c + 0] + bln[c + 0];
        float a1 = (vv[i].y - mean) * rstd * gln[c + 1] + bln[c + 1];
        float a2 = (vv[i].z - mean) * rstd * gln[c + 2] + bln[c + 2];
        float a3 = (vv[i].w - mean) * rstd * gln[c + 3] + bln[c + 3];
        uint2 pk; pk.x = pk2(a0, a1); pk.y = pk2(a2, a3);
        *(uint2*)&ms[row * 264 + c] = pk;
    }
    __syncthreads();

    int wv_ = t >> 6, l = t & 63, l15 = l & 15, l4 = l >> 4;
    f32x4 o[2][4];
#pragma unroll
    for (int mf = 0; mf < 2; mf++)
#pragma unroll
        for (int nf = 0; nf < 4; nf++) o[mf][nf] = (f32x4){0.f, 0.f, 0.f, 0.f};
#pragma unroll
    for (int kk = 0; kk < 8; kk++) {
        bf16x8 a0 = *(const bf16x8*)&ms[l15 * 264 + kk * 32 + l4 * 8];
        bf16x8 a1 = *(const bf16x8*)&ms[(16 + l15) * 264 + kk * 32 + l4 * 8];
#pragma unroll
        for (int nf = 0; nf < 4; nf++) {
            bf16x8 b = *(const bf16x8*)&Wq[(wv_ * 64 + nf * 16 + l15) * 256 + kk * 32 + l4 * 8];
            o[0][nf] = mfma16(a0, b, o[0][nf]);
            o[1][nf] = mfma16(a1, b, o[1][nf]);
        }
    }
#pragma unroll
    for (int nf = 0; nf < 4; nf++) {
        int col = wv_ * 64 + nf * 16 + l15;
        float bb = bq[col];
#pragma unroll
        for (int mf = 0; mf < 2; mf++)
#pragma unroll
            for (int r = 0; r < 4; r++)
                qout[(m0 + mf * 16 + l4 * 4 + r) * 256 + col] = f2bf(o[mf][nf][r] + bb);
    }
}

// ---------------------------------------------------------------------------
// K3 v2: fused attention pass for one (b, 128-token chunk), 1024 blocks:
//     logits -> softmax over S (in-fragment shuffle) -> attn (fp32 out)
//     -> partial updates = attn @ v accumulated via fp32 atomicAdd into upd
// ---------------------------------------------------------------------------
__global__ __launch_bounds__(256) void k_attn(
    const unsigned short* __restrict__ kbf, const unsigned short* __restrict__ vT,
    const unsigned short* __restrict__ qbf, float* __restrict__ attn_out,
    float* __restrict__ upd)
{
    __shared__ unsigned short qs[16 * 264];
    __shared__ unsigned short as_[16 * 136];
    int t = threadIdx.x, l = t & 63, wv_ = t >> 6, l15 = l & 15, l4 = l >> 4;
    int b = blockIdx.x >> 5;
    int chunk = blockIdx.x & 31;
    int tok_base = chunk * 128;

    for (int c = t; c < 512; c += 256) {
        int r = c >> 5, cc = c & 31;
        *(uint4*)&qs[r * 264 + cc * 8] = *(const uint4*)&qbf[(b * 16 + r) * 256 + cc * 8];
    }
    __syncthreads();

    // ---- phase A: logits + softmax over slots; wave covers 32 tokens ----
    int wtok = tok_base + wv_ * 32;
#pragma unroll
    for (int tf = 0; tf < 2; tf++) {
        int tok0 = wtok + tf * 16;
        f32x4 c4 = (f32x4){0.f, 0.f, 0.f, 0.f};
        const unsigned short* krow = kbf + ((long)b * 4096 + tok0 + l15) * 256 + l4 * 8;
#pragma unroll
        for (int kk = 0; kk < 8; kk++) {
            bf16x8 a = *(const bf16x8*)&qs[l15 * 264 + kk * 32 + l4 * 8];
            bf16x8 bb = *(const bf16x8*)&krow[kk * 32];
            c4 = mfma16(a, bb, c4);
        }
#pragma unroll
        for (int r = 0; r < 4; r++) c4[r] *= 0.0625f;   // D^-0.5
        float mx = fmaxf(fmaxf(c4[0], c4[1]), fmaxf(c4[2], c4[3]));
        mx = fmaxf(mx, __shfl_xor(mx, 16));
        mx = fmaxf(mx, __shfl_xor(mx, 32));
        float e[4]; float sm = 0.f;
#pragma unroll
        for (int r = 0; r < 4; r++) { e[r] = __expf(c4[r] - mx); sm += e[r]; }
        sm += __shfl_xor(sm, 16);
        sm += __shfl_xor(sm, 32);
        float inv = 1.0f / sm;
#pragma unroll
        for (int r = 0; r < 4; r++) {
            float av = e[r] * inv;
            int srow = l4 * 4 + r;
            attn_out[((long)b * 16 + srow) * 4096 + tok0 + l15] = av;
            as_[srow * 136 + wv_ * 32 + tf * 16 + l15] = f2bf(av);
        }
    }
    __syncthreads();

    // ---- phase B: partial updates = attn[16 x 128] @ v[128 x 256] ----
    int d0 = wv_ * 64;
    f32x4 u[4];
#pragma unroll
    for (int df = 0; df < 4; df++) u[df] = (f32x4){0.f, 0.f, 0.f, 0.f};
#pragma unroll
    for (int kk = 0; kk < 4; kk++) {
        bf16x8 a = *(const bf16x8*)&as_[l15 * 136 + kk * 32 + l4 * 8];
#pragma unroll
        for (int df = 0; df < 4; df++) {
            bf16x8 bb = *(const bf16x8*)&vT[((long)b * 256 + d0 + df * 16 + l15) * 4096
                                            + tok_base + kk * 32 + l4 * 8];
            u[df] = mfma16(a, bb, u[df]);
        }
    }
#pragma unroll
    for (int df = 0; df < 4; df++)
#pragma unroll
        for (int r = 0; r < 4; r++) {
            int srow = l4 * 4 + r;
            atomicAdd(&upd[(b * 16 + srow) * 256 + d0 + df * 16 + l15], u[df][r]);
        }
}

// ---------------------------------------------------------------------------
// K5: GRU cell: h = GRUCell(updates, slots)
// tile [64 m][64 j], 3 gate column-groups x {W_ih, W_hh}
// ---------------------------------------------------------------------------
__global__ __launch_bounds__(256) void k_gru(
    const float* __restrict__ upd, const float* __restrict__ slots,
    const unsigned short* __restrict__ Wih, const unsigned short* __restrict__ Whh,
    const float* __restrict__ bih, const float* __restrict__ bhh,
    float* __restrict__ hout)
{
    __shared__ unsigned short au[64 * 264], as_[64 * 264];
    int t = threadIdx.x, l = t & 63, wv_ = t >> 6, l15 = l & 15, l4 = l >> 4;
    int m0 = (blockIdx.x >> 2) * 64;
    int j0 = (blockIdx.x & 3) * 64;

    for (int c = t; c < 4096; c += 256) {
        int r = c >> 6, cc = (c & 63) * 4;
        float4 v1 = *(const float4*)&upd[(m0 + r) * 256 + cc];
        float4 v2 = *(const float4*)&slots[(m0 + r) * 256 + cc];
        uint2 p1; p1.x = pk2(v1.x, v1.y); p1.y = pk2(v1.z, v1.w);
        uint2 p2; p2.x = pk2(v2.x, v2.y); p2.y = pk2(v2.z, v2.w);
        *(uint2*)&au[r * 264 + cc] = p1;
        *(uint2*)&as_[r * 264 + cc] = p2;
    }
    __syncthreads();

    int mrow0 = wv_ * 16;
    f32x4 gi[3][4], gh[3][4];
#pragma unroll
    for (int g3 = 0; g3 < 3; g3++)
#pragma unroll
        for (int nf = 0; nf < 4; nf++) {
            gi[g3][nf] = (f32x4){0.f, 0.f, 0.f, 0.f};
            gh[g3][nf] = (f32x4){0.f, 0.f, 0.f, 0.f};
        }
    for (int kk = 0; kk < 8; kk++) {
        bf16x8 a_u = *(const bf16x8*)&au[(mrow0 + l15) * 264 + kk * 32 + l4 * 8];
        bf16x8 a_s = *(const bf16x8*)&as_[(mrow0 + l15) * 264 + kk * 32 + l4 * 8];
#pragma unroll
        for (int g3 = 0; g3 < 3; g3++)
#pragma unroll
            for (int nf = 0; nf < 4; nf++) {
                int wrow = g3 * 256 + j0 + nf * 16 + l15;
                bf16x8 b1 = *(const bf16x8*)&Wih[wrow * 256 + kk * 32 + l4 * 8];
                bf16x8 b2 = *(const bf16x8*)&Whh[wrow * 256 + kk * 32 + l4 * 8];
                gi[g3][nf] = mfma16(a_u, b1, gi[g3][nf]);
                gh[g3][nf] = mfma16(a_s, b2, gh[g3][nf]);
            }
    }
#pragma unroll
    for (int nf = 0; nf < 4; nf++) {
        int col = j0 + nf * 16 + l15;
        float bir = bih[col], biz = bih[256 + col], bin_ = bih[512 + col];
        float bhr = bhh[col], bhz = bhh[256 + col], bhn = bhh[512 + col];
#pragma unroll
        for (int r = 0; r < 4; r++) {
            int row = m0 + mrow0 + l4 * 4 + r;
            float ir = gi[0][nf][r] + bir, iz = gi[1][nf][r] + biz, in_ = gi[2][nf][r] + bin_;
            float hr = gh[0][nf][r] + bhr, hz = gh[1][nf][r] + bhz, hn = gh[2][nf][r] + bhn;
            float rr = sigm(ir + hr);
            float zz = sigm(iz + hz);
            float nn = tanh_(in_ + rr * hn);
            float hp = slots[row * 256 + col];
            hout[row * 256 + col] = (1.f - zz) * nn + zz * hp;
        }
    }
}

// ---------------------------------------------------------------------------
// K6: MLP + residual: out = h + relu(LN(h)@W1^T + b1)@W2^T + b2
// ---------------------------------------------------------------------------
__global__ __launch_bounds__(256) void k_mlp(
    const float* __restrict__ h, const float* __restrict__ gln, const float* __restrict__ bln,
    const unsigned short* __restrict__ W1, const float* __restrict__ b1,
    const unsigned short* __restrict__ W2, const float* __restrict__ b2,
    float* __restrict__ outp)
{
    __shared__ unsigned short ms[32 * 264];
    __shared__ unsigned short fs[32 * 520];
    int t = threadIdx.x;
    int m0 = blockIdx.x * 32;
    int row = t >> 3, sg = t & 7;
    const float4* src = (const float4*)(h + (m0 + row) * 256 + sg * 32);
    float4 vv[8];
    float s = 0.f, ss = 0.f;
#pragma unroll
    for (int i = 0; i < 8; i++) {
        vv[i] = src[i];
        s  += vv[i].x + vv[i].y + vv[i].z + vv[i].w;
        ss += vv[i].x * vv[i].x + vv[i].y * vv[i].y + vv[i].z * vv[i].z + vv[i].w * vv[i].w;
    }
    s  += __shfl_xor(s, 1);  s  += __shfl_xor(s, 2);  s  += __shfl_xor(s, 4);
    ss += __shfl_xor(ss, 1); ss += __shfl_xor(ss, 2); ss += __shfl_xor(ss, 4);
    float mean = s * (1.f / 256.f);
    float rstd = rsqrtf(ss * (1.f / 256.f) - mean * mean + 1e-5f);
#pragma unroll
    for (int i = 0; i < 8; i++) {
        int c = sg * 32 + i * 4;
        float a0 = (vv[i].x - mean) * rstd * gln[c + 0] + bln[c + 0];
        float a1 = (vv[i].y - mean) * rstd * gln[c + 1] + bln[c + 1];
        float a2 = (vv[i].z - mean) * rstd * gln[c + 2] + bln[c + 2];
        float a3 = (vv[i].w - mean) * rstd * gln[c + 3] + bln[c + 3];
        uint2 pk; pk.x = pk2(a0, a1); pk.y = pk2(a2, a3);
        *(uint2*)&ms[row * 264 + c] = pk;
    }
    __syncthreads();

    int wv_ = t >> 6, l = t & 63, l15 = l & 15, l4 = l >> 4;
    // GEMM1: [32][512]
    f32x4 f1[2][8];
#pragma unroll
    for (int mf = 0; mf < 2; mf++)
#pragma unroll
        for (int nf = 0; nf < 8; nf++) f1[mf][nf] = (f32x4){0.f, 0.f, 0.f, 0.f};
    for (int kk = 0; kk < 8; kk++) {
        bf16x8 a0 = *(const bf16x8*)&ms[l15 * 264 + kk * 32 + l4 * 8];
        bf16x8 a1 = *(const bf16x8*)&ms[(16 + l15) * 264 + kk * 32 + l4 * 8];
#pragma unroll
        for (int nf = 0; nf < 8; nf++) {
            bf16x8 b = *(const bf16x8*)&W1[(wv_ * 128 + nf * 16 + l15) * 256 + kk * 32 + l4 * 8];
            f1[0][nf] = mfma16(a0, b, f1[0][nf]);
            f1[1][nf] = mfma16(a1, b, f1[1][nf]);
        }
    }
#pragma unroll
    for (int nf = 0; nf < 8; nf++) {
        int col = wv_ * 128 + nf * 16 + l15;
        float bb = b1[col];
#pragma unroll
        for (int mf = 0; mf < 2; mf++)
#pragma unroll
            for (int r = 0; r < 4; r++)
                fs[(mf * 16 + l4 * 4 + r) * 520 + col] = f2bf(fmaxf(f1[mf][nf][r] + bb, 0.f));
    }
    __syncthreads();

    // GEMM2: [32][256], K=512
    f32x4 o[2][4];
#pragma unroll
    for (int mf = 0; mf < 2; mf++)
#pragma unroll
        for (int nf = 0; nf < 4; nf++) o[mf][nf] = (f32x4){0.f, 0.f, 0.f, 0.f};
    for (int kk = 0; kk < 16; kk++) {
        bf16x8 a0 = *(const bf16x8*)&fs[l15 * 520 + kk * 32 + l4 * 8];
        bf16x8 a1 = *(const bf16x8*)&fs[(16 + l15) * 520 + kk * 32 + l4 * 8];
#pragma unroll
        for (int nf = 0; nf < 4; nf++) {
            bf16x8 b = *(const bf16x8*)&W2[(wv_ * 64 + nf * 16 + l15) * 512 + kk * 32 + l4 * 8];
            o[0][nf] = mfma16(a0, b, o[0][nf]);
            o[1][nf] = mfma16(a1, b, o[1][nf]);
        }
    }
#pragma unroll
    for (int nf = 0; nf < 4; nf++) {
        int col = wv_ * 64 + nf * 16 + l15;
        float bb = b2[col];
#pragma unroll
        for (int mf = 0; mf < 2; mf++)
#pragma unroll
            for (int r = 0; r < 4; r++) {
                int rw = m0 + mf * 16 + l4 * 4 + r;
                outp[rw * 256 + col] = o[mf][nf][r] + bb + h[rw * 256 + col];
            }
    }
}

// ---------------------------------------------------------------------------
extern "C" void kernel_launch(void* const* d_in, const int* in_sizes, int n_in,
                              void* d_out, int out_size, void* d_ws, size_t ws_size,
                              hipStream_t stream)
{
    const float* inputs   = (const float*)d_in[0];
    const float* noise    = (const float*)d_in[1];
    const float* mu       = (const float*)d_in[2];
    const float* sigma    = (const float*)d_in[3];
    const float* ln_in_g  = (const float*)d_in[4];
    const float* ln_in_b  = (const float*)d_in[5];
    const float* ln_s_g   = (const float*)d_in[6];
    const float* ln_s_b   = (const float*)d_in[7];
    const float* ln_m_g   = (const float*)d_in[8];
    const float* ln_m_b   = (const float*)d_in[9];
    const float* Wk       = (const float*)d_in[10];
    const float* bk       = (const float*)d_in[11];
    const float* Wv       = (const float*)d_in[12];
    const float* bv       = (const float*)d_in[13];
    const float* Wq       = (const float*)d_in[14];
    const float* bq       = (const float*)d_in[15];
    const float* W_ih     = (const float*)d_in[16];
    const float* W_hh     = (const float*)d_in[17];
    const float* b_ih     = (const float*)d_in[18];
    const float* b_hh     = (const float*)d_in[19];
    const float* W1       = (const float*)d_in[20];
    const float* b1       = (const float*)d_in[21];
    const float* W2       = (const float*)d_in[22];
    const float* b2       = (const float*)d_in[23];

    char* ws = (char*)d_ws;
    unsigned short* kbf  = (unsigned short*)(ws + 0);              // 67108864 B
    unsigned short* vTb  = (unsigned short*)(ws + 67108864);       // 67108864 B
    float*          slots= (float*)(ws + 134217728);               // 524288 B
    float*          hbuf = (float*)(ws + 134742016);               // 524288 B
    unsigned short* qbf  = (unsigned short*)(ws + 135266304);      // 262144 B
    float*          upd  = (float*)(ws + 135528448);               // 524288 B
    unsigned short* wkb  = (unsigned short*)(ws + 144441344);
    unsigned short* wvb  = (unsigned short*)(ws + 144572416);
    unsigned short* wqb  = (unsigned short*)(ws + 144703488);
    unsigned short* wihb = (unsigned short*)(ws + 144834560);
    unsigned short* whhb = (unsigned short*)(ws + 145227776);
    unsigned short* w1b  = (unsigned short*)(ws + 145620992);
    unsigned short* w2b  = (unsigned short*)(ws + 145883136);
    // total ws use: 146145280 B

    float* out_slots = (float*)d_out;
    float* out_attn  = out_slots + (MS * D_);   // 131072

    k_prep<<<3840, 256, 0, stream>>>(noise, mu, sigma, Wk, Wv, Wq, W_ih, W_hh, W1, W2,
                                     slots, wkb, wvb, wqb, wihb, whhb, w1b, w2b);
    k_lnkv<<<2048, 512, 0, stream>>>(inputs, ln_in_g, ln_in_b, wkb, wvb, bk, bv, kbf, vTb);

    for (int it = 0; it < 3; it++) {
        k_q<<<16, 256, 0, stream>>>(slots, ln_s_g, ln_s_b, wqb, bq, qbf);
        hipMemsetAsync(upd, 0, MS * D_ * sizeof(float), stream);
        k_attn<<<1024, 256, 0, stream>>>(kbf, vTb, qbf, out_attn, upd);
        k_gru<<<32, 256, 0, stream>>>(upd, slots, wihb, whhb, b_ih, b_hh, hbuf);
        k_mlp<<<16, 256, 0, stream>>>(hbuf, ln_m_g, ln_m_b, w1b, b1, w2b, b2,
                                      (it == 2) ? out_slots : slots);
    }
}

// Round 7
// 584.543 us; speedup vs baseline: 1.1532x; 1.0692x over previous
//
#include <hip/hip_runtime.h>
#include <stdint.h>

// Problem constants
#define B_  32
#define N_  4096
#define DIN 256
#define S_  16
#define D_  256
#define H_  512
#define MTOK (B_ * N_)   // 131072 token rows
#define MS   (B_ * S_)   // 512 slot rows

typedef __attribute__((ext_vector_type(8))) short bf16x8;
typedef __attribute__((ext_vector_type(4))) float f32x4;

__device__ __forceinline__ f32x4 mfma16(bf16x8 a, bf16x8 b, f32x4 c) {
    return __builtin_amdgcn_mfma_f32_16x16x32_bf16(a, b, c, 0, 0, 0);
}

__device__ __forceinline__ unsigned short f2bf(float f) {
    union { float f; unsigned int i; } c; c.f = f;
    unsigned int r = (c.i + 0x7fffu + ((c.i >> 16) & 1u)) >> 16;
    return (unsigned short)r;
}
__device__ __forceinline__ unsigned int pk2(float a, float b) {
    return (unsigned int)f2bf(a) | ((unsigned int)f2bf(b) << 16);
}
__device__ __forceinline__ float sigm(float x) { return 1.0f / (1.0f + __expf(-x)); }
__device__ __forceinline__ float tanh_(float x) {
    float e = __expf(-2.0f * fabsf(x));
    float t = (1.0f - e) / (1.0f + e);
    return copysignf(t, x);
}

// Fragment-packed weight layout: for W[R][C] row-major, fragment f=(rt*(C/32)+kk),
// lane l, elems e=0..7:  wp[(f*64+l)*8+e] = W[rt*16+(l&15)][kk*32+(l>>4)*8+e].
// A wave's MFMA B-operand load is then contiguous 1KB (vs 16x64B scattered).

// ---------------------------------------------------------------------------
// K0: slots init + fp32->bf16 packed weight conversion
// ---------------------------------------------------------------------------
__global__ __launch_bounds__(256) void k_prep(
    const float* __restrict__ noise, const float* __restrict__ mu, const float* __restrict__ sigma,
    const float* __restrict__ Wk, const float* __restrict__ Wv, const float* __restrict__ Wq,
    const float* __restrict__ Wih, const float* __restrict__ Whh,
    const float* __restrict__ W1, const float* __restrict__ W2,
    float* __restrict__ slots,
    unsigned short* __restrict__ wkp, unsigned short* __restrict__ wvp,
    unsigned short* __restrict__ wqp, unsigned short* __restrict__ wihp,
    unsigned short* __restrict__ whhp, unsigned short* __restrict__ w1p,
    unsigned short* __restrict__ w2p)
{
    int i = blockIdx.x * 256 + threadIdx.x;
    if (i < 131072) slots[i] = mu[i & 255] + sigma[i & 255] * noise[i];
    int c = i - 131072;
    if (c < 0 || c >= 106496) return;
    const float* src; unsigned short* dst; int cs;   // cs = log2(C/32)
    if (c < 8192)       { src = Wk;  dst = wkp;  cs = 3; }
    else if (c < 16384) { src = Wv;  dst = wvp;  cs = 3; c -= 8192; }
    else if (c < 24576) { src = Wq;  dst = wqp;  cs = 3; c -= 16384; }
    else if (c < 49152) { src = Wih; dst = wihp; cs = 3; c -= 24576; }
    else if (c < 73728) { src = Whh; dst = whhp; cs = 3; c -= 49152; }
    else if (c < 90112) { src = W1;  dst = w1p;  cs = 3; c -= 73728; }
    else                { src = W2;  dst = w2p;  cs = 4; c -= 90112; }
    int l = c & 63, f = c >> 6;
    int kk = f & ((1 << cs) - 1), rt = f >> cs;
    int C = 32 << cs;
    int row = rt * 16 + (l & 15);
    int col = kk * 32 + (l >> 4) * 8;
    const float* s = src + (long)row * C + col;
    unsigned short tmp[8];
#pragma unroll
    for (int e = 0; e < 8; e++) tmp[e] = f2bf(s[e]);
    *(uint4*)&dst[(long)c * 8] = *(const uint4*)tmp;
}

// ---------------------------------------------------------------------------
// K1 v4: fused LayerNorm(inputs) + k/v projections -> fragment-packed outputs.
// kpk[b][tokTile(256)][kk(8)][lane(64)][8]  (= q@k^T B-operand order)
// vpk[b][tokBlk(128)][dTile(16)][lane(64)][8] (= attn@v B-operand order)
// 512 threads / 8 waves; per-wave 64 rows x 64 cols; packed weight loads.
// ---------------------------------------------------------------------------
__global__ __launch_bounds__(512, 4) void k_lnkv(
    const float* __restrict__ inp, const float* __restrict__ gln, const float* __restrict__ bln,
    const unsigned short* __restrict__ wkp, const unsigned short* __restrict__ wvp,
    const float* __restrict__ bk, const float* __restrict__ bv,
    unsigned short* __restrict__ kpk, unsigned short* __restrict__ vpk)
{
    __shared__ unsigned short xa[64 * 264];    // LN out, then k C-stage (33792 B)
    __shared__ unsigned short vst[64 * 264];   // v C-stage (33792 B)
    __shared__ float gl[256], bl[256];

    int t = threadIdx.x;
    long m0 = (long)blockIdx.x * 64;
    if (t < 256) { gl[t] = gln[t]; bl[t] = bln[t]; }

    // ---- LN stage ----
    int row = t >> 3, seg = t & 7;
    const float4* src = (const float4*)(inp + (m0 + row) * 256 + seg * 32);
    float4 vv[8];
    float s = 0.f, ss = 0.f;
#pragma unroll
    for (int i = 0; i < 8; i++) {
        vv[i] = src[i];
        s  += vv[i].x + vv[i].y + vv[i].z + vv[i].w;
        ss += vv[i].x * vv[i].x + vv[i].y * vv[i].y + vv[i].z * vv[i].z + vv[i].w * vv[i].w;
    }
    s  += __shfl_xor(s, 1);  s  += __shfl_xor(s, 2);  s  += __shfl_xor(s, 4);
    ss += __shfl_xor(ss, 1); ss += __shfl_xor(ss, 2); ss += __shfl_xor(ss, 4);
    float mean = s * (1.f / 256.f);
    float rstd = rsqrtf(ss * (1.f / 256.f) - mean * mean + 1e-5f);
    __syncthreads();
#pragma unroll
    for (int i = 0; i < 8; i++) {
        int c = seg * 32 + i * 4;
        float a0 = (vv[i].x - mean) * rstd * gl[c + 0] + bl[c + 0];
        float a1 = (vv[i].y - mean) * rstd * gl[c + 1] + bl[c + 1];
        float a2 = (vv[i].z - mean) * rstd * gl[c + 2] + bl[c + 2];
        float a3 = (vv[i].w - mean) * rstd * gl[c + 3] + bl[c + 3];
        uint2 pk; pk.x = pk2(a0, a1); pk.y = pk2(a2, a3);
        *(uint2*)&xa[row * 264 + c] = pk;
    }
    __syncthreads();

    // ---- GEMM: wave w (<4: k, >=4: v), packed weight fragments ----
    int wv_ = t >> 6, l = t & 63, l15 = l & 15, l4 = l >> 4;
    const unsigned short* Wsel = (wv_ < 4) ? wkp : wvp;
    int ct0 = (wv_ & 3) * 4;   // col-tile base (4 tiles of 16 cols)
    f32x4 acc[4][4];
#pragma unroll
    for (int mf = 0; mf < 4; mf++)
#pragma unroll
        for (int nf = 0; nf < 4; nf++) acc[mf][nf] = (f32x4){0.f, 0.f, 0.f, 0.f};

#pragma unroll
    for (int kk = 0; kk < 8; kk++) {
        bf16x8 a[4];
#pragma unroll
        for (int mf = 0; mf < 4; mf++)
            a[mf] = *(const bf16x8*)&xa[(mf * 16 + l15) * 264 + kk * 32 + l4 * 8];
#pragma unroll
        for (int nf = 0; nf < 4; nf++) {
            bf16x8 b = *(const bf16x8*)&Wsel[(((ct0 + nf) * 8 + kk) * 64 + l) * 8];
#pragma unroll
            for (int mf = 0; mf < 4; mf++) acc[mf][nf] = mfma16(a[mf], b, acc[mf][nf]);
        }
    }
    __syncthreads();  // xa dead; reuse for k stage

    // ---- stage both C tiles (k-waves -> xa, v-waves -> vst), ONE barrier ----
    if (wv_ < 4) {
#pragma unroll
        for (int nf = 0; nf < 4; nf++) {
            int col = (ct0 + nf) * 16 + l15;
            float bias = bk[col];
#pragma unroll
            for (int mf = 0; mf < 4; mf++)
#pragma unroll
                for (int r = 0; r < 4; r++)
                    xa[(mf * 16 + l4 * 4 + r) * 264 + col] = f2bf(acc[mf][nf][r] + bias);
        }
    } else {
#pragma unroll
        for (int nf = 0; nf < 4; nf++) {
            int col = (ct0 + nf) * 16 + l15;
            float bias = bv[col];
#pragma unroll
            for (int mf = 0; mf < 4; mf++)
#pragma unroll
                for (int r = 0; r < 4; r++)
                    vst[(mf * 16 + l4 * 4 + r) * 264 + col] = f2bf(acc[mf][nf][r] + bias);
        }
    }
    __syncthreads();

    int bb   = (int)(m0 >> 12);
    int ttl0 = ((int)(m0 & 4095)) >> 4;   // tokTile base within b (4 tiles)
    int tb0  = ((int)(m0 & 4095)) >> 5;   // tokBlk base within b (2 blks)

    // ---- kpk copy-out: 2048 x 16B, fully coalesced ----
    for (int c = t; c < 2048; c += 512) {
        int lane = c & 63, kk2 = (c >> 6) & 7, ttl = c >> 9;
        uint4 val = *(const uint4*)&xa[(ttl * 16 + (lane & 15)) * 264 + kk2 * 32 + (lane >> 4) * 8];
        *(uint4*)&kpk[((((long)bb * 256 + ttl0 + ttl) * 8 + kk2) * 64 + lane) * 8] = val;
    }
    // ---- vpk copy-out: transpose gather from vst, coalesced store ----
    for (int c = t; c < 2048; c += 512) {
        int lane = c & 63, dt = (c >> 6) & 15, tb = c >> 10;
        int d = dt * 16 + (lane & 15);
        int tokb = tb * 32 + (lane >> 4) * 8;
        unsigned short tmp[8];
#pragma unroll
        for (int e = 0; e < 8; e++) tmp[e] = vst[(tokb + e) * 264 + d];
        *(uint4*)&vpk[((((long)bb * 128 + tb0 + tb) * 16 + dt) * 64 + lane) * 8] =
            *(const uint4*)tmp;
    }
}

// ---------------------------------------------------------------------------
// K2: q = LN(slots)@Wq^T + bq  -> q_bf16 [512][256] (packed Wq loads)
// ---------------------------------------------------------------------------
__global__ __launch_bounds__(256) void k_q(
    const float* __restrict__ slots, const float* __restrict__ gln, const float* __restrict__ bln,
    const unsigned short* __restrict__ wqp, const float* __restrict__ bq,
    unsigned short* __restrict__ qout)
{
    __shared__ unsigned short ms[32 * 264];
    int t = threadIdx.x;
    int m0 = blockIdx.x * 32;
    int row = t >> 3, sg = t & 7;
    const float4* src = (const float4*)(slots + (m0 + row) * 256 + sg * 32);
    float4 vv[8];
    float s = 0.f, ss = 0.f;
#pragma unroll
    for (int i = 0; i < 8; i++) {
        vv[i] = src[i];
        s  += vv[i].x + vv[i].y + vv[i].z + vv[i].w;
        ss += vv[i].x * vv[i].x + vv[i].y * vv[i].y + vv[i].z * vv[i].z + vv[i].w * vv[i].w;
    }
    s  += __shfl_xor(s, 1);  s  += __shfl_xor(s, 2);  s  += __shfl_xor(s, 4);
    ss += __shfl_xor(ss, 1); ss += __shfl_xor(ss, 2); ss += __shfl_xor(ss, 4);
    float mean = s * (1.f / 256.f);
    float rstd = rsqrtf(ss * (1.f / 256.f) - mean * mean + 1e-5f);
#pragma unroll
    for (int i = 0; i < 8; i++) {
        int c = sg * 32 + i * 4;
        float a0 = (vv[i].x - mean) * rstd * gln[c + 0] + bln[c + 0];
        float a1 = (vv[i].y - mean) * rstd * gln[c + 1] + bln[c + 1];
        float a2 = (vv[i].z - mean) * rstd * gln[c + 2] + bln[c + 2];
        float a3 = (vv[i].w - mean) * rstd * gln[c + 3] + bln[c + 3];
        uint2 pk; pk.x = pk2(a0, a1); pk.y = pk2(a2, a3);
        *(uint2*)&ms[row * 264 + c] = pk;
    }
    __syncthreads();

    int wv_ = t >> 6, l = t & 63, l15 = l & 15, l4 = l >> 4;
    f32x4 o[2][4];
#pragma unroll
    for (int mf = 0; mf < 2; mf++)
#pragma unroll
        for (int nf = 0; nf < 4; nf++) o[mf][nf] = (f32x4){0.f, 0.f, 0.f, 0.f};
#pragma unroll
    for (int kk = 0; kk < 8; kk++) {
        bf16x8 a0 = *(const bf16x8*)&ms[l15 * 264 + kk * 32 + l4 * 8];
        bf16x8 a1 = *(const bf16x8*)&ms[(16 + l15) * 264 + kk * 32 + l4 * 8];
#pragma unroll
        for (int nf = 0; nf < 4; nf++) {
            bf16x8 b = *(const bf16x8*)&wqp[(((wv_ * 4 + nf) * 8 + kk) * 64 + l) * 8];
            o[0][nf] = mfma16(a0, b, o[0][nf]);
            o[1][nf] = mfma16(a1, b, o[1][nf]);
        }
    }
#pragma unroll
    for (int nf = 0; nf < 4; nf++) {
        int col = wv_ * 64 + nf * 16 + l15;
        float bb = bq[col];
#pragma unroll
        for (int mf = 0; mf < 2; mf++)
#pragma unroll
            for (int r = 0; r < 4; r++)
                qout[(m0 + mf * 16 + l4 * 4 + r) * 256 + col] = f2bf(o[mf][nf][r] + bb);
    }
}

// ---------------------------------------------------------------------------
// K3 v3: fused attention for one (b, 128-token chunk); packed k/v fragments
// so every global MFMA-operand load is contiguous 1KB. attn fp32 staged in
// LDS then written in 512B row segments.
// ---------------------------------------------------------------------------
__global__ __launch_bounds__(256) void k_attn(
    const unsigned short* __restrict__ kpk, const unsigned short* __restrict__ vpk,
    const unsigned short* __restrict__ qbf, float* __restrict__ attn_out,
    float* __restrict__ upd)
{
    __shared__ unsigned short qs[16 * 264];
    __shared__ unsigned short as_[16 * 136];
    __shared__ float att_f[16 * 132];
    int t = threadIdx.x, l = t & 63, wv_ = t >> 6, l15 = l & 15, l4 = l >> 4;
    int b = blockIdx.x >> 5;
    int chunk = blockIdx.x & 31;
    int tok_base = chunk * 128;

    for (int c = t; c < 512; c += 256) {
        int r = c >> 5, cc = c & 31;
        *(uint4*)&qs[r * 264 + cc * 8] = *(const uint4*)&qbf[(b * 16 + r) * 256 + cc * 8];
    }
    __syncthreads();

    // ---- phase A: logits + softmax over slots; wave covers 32 tokens ----
#pragma unroll
    for (int tf = 0; tf < 2; tf++) {
        int tt = (tok_base >> 4) + wv_ * 2 + tf;          // tokTile within b
        const unsigned short* kfrag = kpk + ((long)(b * 256 + tt) * 8) * 512;
        f32x4 c4 = (f32x4){0.f, 0.f, 0.f, 0.f};
#pragma unroll
        for (int kk = 0; kk < 8; kk++) {
            bf16x8 a = *(const bf16x8*)&qs[l15 * 264 + kk * 32 + l4 * 8];
            bf16x8 bb = *(const bf16x8*)&kfrag[(kk * 64 + l) * 8];
            c4 = mfma16(a, bb, c4);
        }
#pragma unroll
        for (int r = 0; r < 4; r++) c4[r] *= 0.0625f;   // D^-0.5
        float mx = fmaxf(fmaxf(c4[0], c4[1]), fmaxf(c4[2], c4[3]));
        mx = fmaxf(mx, __shfl_xor(mx, 16));
        mx = fmaxf(mx, __shfl_xor(mx, 32));
        float e[4]; float sm = 0.f;
#pragma unroll
        for (int r = 0; r < 4; r++) { e[r] = __expf(c4[r] - mx); sm += e[r]; }
        sm += __shfl_xor(sm, 16);
        sm += __shfl_xor(sm, 32);
        float inv = 1.0f / sm;
#pragma unroll
        for (int r = 0; r < 4; r++) {
            float av = e[r] * inv;
            int srow = l4 * 4 + r;
            int tloc = wv_ * 32 + tf * 16 + l15;
            att_f[srow * 132 + tloc] = av;
            as_[srow * 136 + tloc] = f2bf(av);
        }
    }
    __syncthreads();

    // ---- attn_out copy: 512B contiguous per slot row ----
    for (int c = t; c < 2048; c += 256) {
        int row = c >> 7, tok = c & 127;
        attn_out[((long)b * 16 + row) * 4096 + tok_base + tok] = att_f[row * 132 + tok];
    }

    // ---- phase B: updates += attn[16x128] @ v[128x256] ----
    int tbase = chunk * 4;                                 // tokBlk base (4 blks of 32)
    f32x4 u[4];
#pragma unroll
    for (int df = 0; df < 4; df++) u[df] = (f32x4){0.f, 0.f, 0.f, 0.f};
#pragma unroll
    for (int kk = 0; kk < 4; kk++) {
        bf16x8 a = *(const bf16x8*)&as_[l15 * 136 + kk * 32 + l4 * 8];
#pragma unroll
        for (int df = 0; df < 4; df++) {
            int dTile = wv_ * 4 + df;
            long f = (long)(b * 128 + tbase + kk) * 16 + dTile;
            bf16x8 bb = *(const bf16x8*)&vpk[(f * 64 + l) * 8];
            u[df] = mfma16(a, bb, u[df]);
        }
    }
#pragma unroll
    for (int df = 0; df < 4; df++)
#pragma unroll
        for (int r = 0; r < 4; r++) {
            int srow = l4 * 4 + r;
            atomicAdd(&upd[(b * 16 + srow) * 256 + wv_ * 64 + df * 16 + l15], u[df][r]);
        }
}

// ---------------------------------------------------------------------------
// K5: GRU cell (packed Wih/Whh loads)
// ---------------------------------------------------------------------------
__global__ __launch_bounds__(256) void k_gru(
    const float* __restrict__ upd, const float* __restrict__ slots,
    const unsigned short* __restrict__ wihp, const unsigned short* __restrict__ whhp,
    const float* __restrict__ bih, const float* __restrict__ bhh,
    float* __restrict__ hout)
{
    __shared__ unsigned short au[64 * 264], as_[64 * 264];
    int t = threadIdx.x, l = t & 63, wv_ = t >> 6, l15 = l & 15, l4 = l >> 4;
    int m0 = (blockIdx.x >> 2) * 64;
    int j0 = (blockIdx.x & 3) * 64;

    for (int c = t; c < 4096; c += 256) {
        int r = c >> 6, cc = (c & 63) * 4;
        float4 v1 = *(const float4*)&upd[(m0 + r) * 256 + cc];
        float4 v2 = *(const float4*)&slots[(m0 + r) * 256 + cc];
        uint2 p1; p1.x = pk2(v1.x, v1.y); p1.y = pk2(v1.z, v1.w);
        uint2 p2; p2.x = pk2(v2.x, v2.y); p2.y = pk2(v2.z, v2.w);
        *(uint2*)&au[r * 264 + cc] = p1;
        *(uint2*)&as_[r * 264 + cc] = p2;
    }
    __syncthreads();

    int mrow0 = wv_ * 16;
    f32x4 gi[3][4], gh[3][4];
#pragma unroll
    for (int g3 = 0; g3 < 3; g3++)
#pragma unroll
        for (int nf = 0; nf < 4; nf++) {
            gi[g3][nf] = (f32x4){0.f, 0.f, 0.f, 0.f};
            gh[g3][nf] = (f32x4){0.f, 0.f, 0.f, 0.f};
        }
#pragma unroll
    for (int kk = 0; kk < 8; kk++) {
        bf16x8 a_u = *(const bf16x8*)&au[(mrow0 + l15) * 264 + kk * 32 + l4 * 8];
        bf16x8 a_s = *(const bf16x8*)&as_[(mrow0 + l15) * 264 + kk * 32 + l4 * 8];
#pragma unroll
        for (int g3 = 0; g3 < 3; g3++)
#pragma unroll
            for (int nf = 0; nf < 4; nf++) {
                int ct = g3 * 16 + (j0 >> 4) + nf;
                bf16x8 b1 = *(const bf16x8*)&wihp[((ct * 8 + kk) * 64 + l) * 8];
                bf16x8 b2 = *(const bf16x8*)&whhp[((ct * 8 + kk) * 64 + l) * 8];
                gi[g3][nf] = mfma16(a_u, b1, gi[g3][nf]);
                gh[g3][nf] = mfma16(a_s, b2, gh[g3][nf]);
            }
    }
#pragma unroll
    for (int nf = 0; nf < 4; nf++) {
        int col = j0 + nf * 16 + l15;
        float bir = bih[col], biz = bih[256 + col], bin_ = bih[512 + col];
        float bhr = bhh[col], bhz = bhh[256 + col], bhn = bhh[512 + col];
#pragma unroll
        for (int r = 0; r < 4; r++) {
            int row = m0 + mrow0 + l4 * 4 + r;
            float ir = gi[0][nf][r] + bir, iz = gi[1][nf][r] + biz, in_ = gi[2][nf][r] + bin_;
            float hr = gh[0][nf][r] + bhr, hz = gh[1][nf][r] + bhz, hn = gh[2][nf][r] + bhn;
            float rr = sigm(ir + hr);
            float zz = sigm(iz + hz);
            float nn = tanh_(in_ + rr * hn);
            float hp = slots[row * 256 + col];
            hout[row * 256 + col] = (1.f - zz) * nn + zz * hp;
        }
    }
}

// ---------------------------------------------------------------------------
// K6: MLP + residual (packed W1/W2 loads)
// ---------------------------------------------------------------------------
__global__ __launch_bounds__(256) void k_mlp(
    const float* __restrict__ h, const float* __restrict__ gln, const float* __restrict__ bln,
    const unsigned short* __restrict__ w1p, const float* __restrict__ b1,
    const unsigned short* __restrict__ w2p, const float* __restrict__ b2,
    float* __restrict__ outp)
{
    __shared__ unsigned short ms[32 * 264];
    __shared__ unsigned short fs[32 * 520];
    int t = threadIdx.x;
    int m0 = blockIdx.x * 32;
    int row = t >> 3, sg = t & 7;
    const float4* src = (const float4*)(h + (m0 + row) * 256 + sg * 32);
    float4 vv[8];
    float s = 0.f, ss = 0.f;
#pragma unroll
    for (int i = 0; i < 8; i++) {
        vv[i] = src[i];
        s  += vv[i].x + vv[i].y + vv[i].z + vv[i].w;
        ss += vv[i].x * vv[i].x + vv[i].y * vv[i].y + vv[i].z * vv[i].z + vv[i].w * vv[i].w;
    }
    s  += __shfl_xor(s, 1);  s  += __shfl_xor(s, 2);  s  += __shfl_xor(s, 4);
    ss += __shfl_xor(ss, 1); ss += __shfl_xor(ss, 2); ss += __shfl_xor(ss, 4);
    float mean = s * (1.f / 256.f);
    float rstd = rsqrtf(ss * (1.f / 256.f) - mean * mean + 1e-5f);
#pragma unroll
    for (int i = 0; i < 8; i++) {
        int c = sg * 32 + i * 4;
        float a0 = (vv[i].x - mean) * rstd * gln[c + 0] + bln[c + 0];
        float a1 = (vv[i].y - mean) * rstd * gln[c + 1] + bln[c + 1];
        float a2 = (vv[i].z - mean) * rstd * gln[c + 2] + bln[c + 2];
        float a3 = (vv[i].w - mean) * rstd * gln[c + 3] + bln[c + 3];
        uint2 pk; pk.x = pk2(a0, a1); pk.y = pk2(a2, a3);
        *(uint2*)&ms[row * 264 + c] = pk;
    }
    __syncthreads();

    int wv_ = t >> 6, l = t & 63, l15 = l & 15, l4 = l >> 4;
    // GEMM1: [32][512]
    f32x4 f1[2][8];
#pragma unroll
    for (int mf = 0; mf < 2; mf++)
#pragma unroll
        for (int nf = 0; nf < 8; nf++) f1[mf][nf] = (f32x4){0.f, 0.f, 0.f, 0.f};
#pragma unroll
    for (int kk = 0; kk < 8; kk++) {
        bf16x8 a0 = *(const bf16x8*)&ms[l15 * 264 + kk * 32 + l4 * 8];
        bf16x8 a1 = *(const bf16x8*)&ms[(16 + l15) * 264 + kk * 32 + l4 * 8];
#pragma unroll
        for (int nf = 0; nf < 8; nf++) {
            bf16x8 b = *(const bf16x8*)&w1p[(((wv_ * 8 + nf) * 8 + kk) * 64 + l) * 8];
            f1[0][nf] = mfma16(a0, b, f1[0][nf]);
            f1[1][nf] = mfma16(a1, b, f1[1][nf]);
        }
    }
#pragma unroll
    for (int nf = 0; nf < 8; nf++) {
        int col = wv_ * 128 + nf * 16 + l15;
        float bb = b1[col];
#pragma unroll
        for (int mf = 0; mf < 2; mf++)
#pragma unroll
            for (int r = 0; r < 4; r++)
                fs[(mf * 16 + l4 * 4 + r) * 520 + col] = f2bf(fmaxf(f1[mf][nf][r] + bb, 0.f));
    }
    __syncthreads();

    // GEMM2: [32][256], K=512
    f32x4 o[2][4];
#pragma unroll
    for (int mf = 0; mf < 2; mf++)
#pragma unroll
        for (int nf = 0; nf < 4; nf++) o[mf][nf] = (f32x4){0.f, 0.f, 0.f, 0.f};
#pragma unroll
    for (int kk = 0; kk < 16; kk++) {
        bf16x8 a0 = *(const bf16x8*)&fs[l15 * 520 + kk * 32 + l4 * 8];
        bf16x8 a1 = *(const bf16x8*)&fs[(16 + l15) * 520 + kk * 32 + l4 * 8];
#pragma unroll
        for (int nf = 0; nf < 4; nf++) {
            bf16x8 b = *(const bf16x8*)&w2p[(((wv_ * 4 + nf) * 16 + kk) * 64 + l) * 8];
            o[0][nf] = mfma16(a0, b, o[0][nf]);
            o[1][nf] = mfma16(a1, b, o[1][nf]);
        }
    }
#pragma unroll
    for (int nf = 0; nf < 4; nf++) {
        int col = wv_ * 64 + nf * 16 + l15;
        float bb = b2[col];
#pragma unroll
        for (int mf = 0; mf < 2; mf++)
#pragma unroll
            for (int r = 0; r < 4; r++) {
                int rw = m0 + mf * 16 + l4 * 4 + r;
                outp[rw * 256 + col] = o[mf][nf][r] + bb + h[rw * 256 + col];
            }
    }
}

// ---------------------------------------------------------------------------
extern "C" void kernel_launch(void* const* d_in, const int* in_sizes, int n_in,
                              void* d_out, int out_size, void* d_ws, size_t ws_size,
                              hipStream_t stream)
{
    const float* inputs   = (const float*)d_in[0];
    const float* noise    = (const float*)d_in[1];
    const float* mu       = (const float*)d_in[2];
    const float* sigma    = (const float*)d_in[3];
    const float* ln_in_g  = (const float*)d_in[4];
    const float* ln_in_b  = (const float*)d_in[5];
    const float* ln_s_g   = (const float*)d_in[6];
    const float* ln_s_b   = (const float*)d_in[7];
    const float* ln_m_g   = (const float*)d_in[8];
    const float* ln_m_b   = (const float*)d_in[9];
    const float* Wk       = (const float*)d_in[10];
    const float* bk       = (const float*)d_in[11];
    const float* Wv       = (const float*)d_in[12];
    const float* bv       = (const float*)d_in[13];
    const float* Wq       = (const float*)d_in[14];
    const float* bq       = (const float*)d_in[15];
    const float* W_ih     = (const float*)d_in[16];
    const float* W_hh     = (const float*)d_in[17];
    const float* b_ih     = (const float*)d_in[18];
    const float* b_hh     = (const float*)d_in[19];
    const float* W1       = (const float*)d_in[20];
    const float* b1       = (const float*)d_in[21];
    const float* W2       = (const float*)d_in[22];
    const float* b2       = (const float*)d_in[23];

    char* ws = (char*)d_ws;
    unsigned short* kpk  = (unsigned short*)(ws + 0);              // 67108864 B
    unsigned short* vpk  = (unsigned short*)(ws + 67108864);       // 67108864 B
    float*          slots= (float*)(ws + 134217728);               // 524288 B
    float*          hbuf = (float*)(ws + 134742016);               // 524288 B
    unsigned short* qbf  = (unsigned short*)(ws + 135266304);      // 262144 B
    float*          upd  = (float*)(ws + 135528448);               // 524288 B
    unsigned short* wkp  = (unsigned short*)(ws + 144441344);      // 131072 B
    unsigned short* wvp  = (unsigned short*)(ws + 144572416);
    unsigned short* wqp  = (unsigned short*)(ws + 144703488);
    unsigned short* wihp = (unsigned short*)(ws + 144834560);      // 393216 B
    unsigned short* whhp = (unsigned short*)(ws + 145227776);
    unsigned short* w1p  = (unsigned short*)(ws + 145620992);      // 262144 B
    unsigned short* w2p  = (unsigned short*)(ws + 145883136);      // 262144 B
    // total ws use: 146145280 B

    float* out_slots = (float*)d_out;
    float* out_attn  = out_slots + (MS * D_);   // 131072

    k_prep<<<928, 256, 0, stream>>>(noise, mu, sigma, Wk, Wv, Wq, W_ih, W_hh, W1, W2,
                                    slots, wkp, wvp, wqp, wihp, whhp, w1p, w2p);
    k_lnkv<<<2048, 512, 0, stream>>>(inputs, ln_in_g, ln_in_b, wkp, wvp, bk, bv, kpk, vpk);

    for (int it = 0; it < 3; it++) {
        k_q<<<16, 256, 0, stream>>>(slots, ln_s_g, ln_s_b, wqp, bq, qbf);
        hipMemsetAsync(upd, 0, MS * D_ * sizeof(float), stream);
        k_attn<<<1024, 256, 0, stream>>>(kpk, vpk, qbf, out_attn, upd);
        k_gru<<<32, 256, 0, stream>>>(upd, slots, wihp, whhp, b_ih, b_hh, hbuf);
        k_mlp<<<16, 256, 0, stream>>>(hbuf, ln_m_g, ln_m_b, w1p, b1, w2p, b2,
                                      (it == 2) ? out_slots : slots);
    }
}